// Round 1
// 1300.049 us; speedup vs baseline: 1.1125x; 1.1125x over previous
//
#include <hip/hip_runtime.h>
#include <hip/hip_bf16.h>

#define NN 512
#define TT 60
#define DFF 6
#define EE 8192
#define TN (TT*NN)
#define TCH 10          // t-chunk size
#define NCHK 6          // number of t-chunks
#define SCALEV 0.125f
#define NEGV -1.0e10f

typedef __hip_bfloat16 bf16;
using bfrag8 = __attribute__((ext_vector_type(8))) short;   // 8 bf16 (4 VGPRs)
using facc4  = __attribute__((ext_vector_type(4))) float;   // 4 f32 acc

__device__ __forceinline__ float b2f(bf16 v){ return __bfloat162float(v); }
__device__ __forceinline__ bf16 f2b(float v){ return __float2bfloat16(v); }
__device__ __forceinline__ float lk(float x){ return x >= 0.f ? x : 0.01f*x; }
__device__ __forceinline__ float sgm(float x){ return 1.f/(1.f+__expf(-x)); }

__device__ __forceinline__ float ldf(const float* p, long i){ return p[i]; }
__device__ __forceinline__ float ldf(const bf16* p, long i){ return b2f(p[i]); }
__device__ __forceinline__ void stf(float* p, long i, float v){ p[i] = v; }
__device__ __forceinline__ void stf(bf16* p, long i, float v){ p[i] = f2b(v); }

__device__ __forceinline__ float wsum64(float v){
  #pragma unroll
  for (int off = 32; off; off >>= 1) v += __shfl_xor(v, off, 64);
  return v;
}
__device__ __forceinline__ float wmax64(float v){
  #pragma unroll
  for (int off = 32; off; off >>= 1) v = fmaxf(v, __shfl_xor(v, off, 64));
  return v;
}

// ---------------- adjacency bitmask ----------------
__global__ __launch_bounds__(256) void k_zero_u32(unsigned int* __restrict__ p, int n){
  int i = blockIdx.x*256 + threadIdx.x;
  if (i < n) p[i] = 0u;
}
__global__ __launch_bounds__(256) void k_scatter_bits(const int* __restrict__ ei, unsigned int* __restrict__ msk){
  int e = blockIdx.x*256 + threadIdx.x;
  if (e < EE) {
    int u = ei[e], v = ei[EE + e];
    atomicOr(&msk[u*16 + (v >> 5)], 1u << (v & 31));
  }
}

// ---------------- pack: Wc f32 = qs|ks|v|vs ; bcV = vb|vsb ; Wqk f32 = q|k ----------------
__global__ __launch_bounds__(256) void k_pack(
  const float* __restrict__ qsw, const float* __restrict__ ksw,
  const float* __restrict__ vw, const float* __restrict__ vsw,
  const float* __restrict__ vb, const float* __restrict__ vsb,
  const float* __restrict__ qw, const float* __restrict__ kw,
  float* __restrict__ Wc, float* __restrict__ bcV, float* __restrict__ Wqk)
{
  int idx = blockIdx.x*256 + threadIdx.x;
  if (idx < 4*4096) {
    int which = idx >> 12, rem = idx & 4095;
    const float* s = (which==0)?qsw:(which==1)?ksw:(which==2)?vw:vsw;
    Wc[idx] = s[rem];
  } else if (idx < 4*4096 + 128) {
    int o = idx - 4*4096;
    bcV[o] = (o < 64) ? vb[o] : vsb[o-64];
  } else if (idx < 4*4096 + 128 + 8192) {
    int i2 = idx - (4*4096 + 128);
    Wqk[i2] = (i2 < 4096) ? qw[i2] : kw[i2 - 4096];
  }
}

// ---------------- fc_in: np-exact fp32 (seq-FMA over k, bias added after) ----------------
__global__ __launch_bounds__(256) void k_fcin(
  const float* __restrict__ x, const float* __restrict__ w, const float* __restrict__ b,
  float* __restrict__ xs, float* __restrict__ resid)
{
  long idx = (long)blockIdx.x*256 + threadIdx.x;   // < TN*64
  int o = idx & 63;
  long r = idx >> 6;                // r = t*NN + n
  int t = (int)(r / NN), n = (int)(r % NN);
  const float* xr = x + ((long)n*TT + t)*DFF;
  const float* wr = w + o*DFF;
  float acc = 0.f;
  #pragma unroll
  for (int j = 0; j < DFF; ++j) acc = fmaf(xr[j], wr[j], acc);
  float h = __fadd_rn(acc, b[o]);
  xs[idx] = h;
  resid[idx] = h;
}

// ---------------- np-exact q|k projection (seq-FMA over k=0..63) ----------------
// qkx[rc][128] = h[rc] @ Wqk^T, rc chunk-local row; A = xs chunk base (row-major 64)
__global__ __launch_bounds__(256) void k_qkx(
  const float* __restrict__ A, const float* __restrict__ Wqk, float* __restrict__ qkx)
{
  __shared__ float As[64][65];
  __shared__ float Bs[64][65];
  int rt = blockIdx.x, bcn = blockIdx.y;
  int tid = threadIdx.x;
  int tx = tid & 15, ty = tid >> 4;
  float acc[4][4] = {{0.f}};
  #pragma unroll
  for (int i = 0; i < 16; ++i) {
    int idx = i*256 + tid;
    int m = idx >> 6, kk = idx & 63;
    As[kk][m] = A[(long)(rt*64 + m)*64 + kk];
    Bs[kk][m] = Wqk[(long)(bcn*64 + m)*64 + kk];
  }
  __syncthreads();
  for (int kk = 0; kk < 64; ++kk) {
    float a0 = As[kk][ty*4+0], a1 = As[kk][ty*4+1], a2 = As[kk][ty*4+2], a3 = As[kk][ty*4+3];
    float b0 = Bs[kk][tx*4+0], b1 = Bs[kk][tx*4+1], b2v = Bs[kk][tx*4+2], b3 = Bs[kk][tx*4+3];
    acc[0][0] = fmaf(a0,b0,acc[0][0]); acc[0][1] = fmaf(a0,b1,acc[0][1]); acc[0][2] = fmaf(a0,b2v,acc[0][2]); acc[0][3] = fmaf(a0,b3,acc[0][3]);
    acc[1][0] = fmaf(a1,b0,acc[1][0]); acc[1][1] = fmaf(a1,b1,acc[1][1]); acc[1][2] = fmaf(a1,b2v,acc[1][2]); acc[1][3] = fmaf(a1,b3,acc[1][3]);
    acc[2][0] = fmaf(a2,b0,acc[2][0]); acc[2][1] = fmaf(a2,b1,acc[2][1]); acc[2][2] = fmaf(a2,b2v,acc[2][2]); acc[2][3] = fmaf(a2,b3,acc[2][3]);
    acc[3][0] = fmaf(a3,b0,acc[3][0]); acc[3][1] = fmaf(a3,b1,acc[3][1]); acc[3][2] = fmaf(a3,b2v,acc[3][2]); acc[3][3] = fmaf(a3,b3,acc[3][3]);
  }
  #pragma unroll
  for (int i = 0; i < 4; ++i) {
    long ro = (long)(rt*64 + ty*4 + i)*128 + bcn*64 + tx*4;
    #pragma unroll
    for (int j = 0; j < 4; ++j) qkx[ro + j] = acc[i][j];
  }
}

// ---------------- generic projection GEMM (fp32, tolerant paths) ----------------
template<typename TA, typename TC>
__global__ __launch_bounds__(256) void k_gemm(
  const TA* __restrict__ A, const float* __restrict__ B, const float* __restrict__ bias,
  TC* __restrict__ C, int KD, int NC, int gather)
{
  __shared__ float As[64][65];
  __shared__ float Bs[64][65];
  int rt = blockIdx.x, bcn = blockIdx.y;
  int tid = threadIdx.x;
  int tx = tid & 15, ty = tid >> 4;
  float acc[4][4] = {{0.f}};
  int nch = KD >> 6;
  for (int kc = 0; kc < nch; ++kc) {
    __syncthreads();
    #pragma unroll
    for (int i = 0; i < 16; ++i) {
      int idx = i*256 + tid;
      int m = idx >> 6, kk = idx & 63;
      long aoff;
      int r = rt*64 + m;
      if (gather) { int n = r / TT, t = r - n*TT; aoff = ((long)t*NN + n)*64 + kk; }
      else aoff = (long)r*KD + kc*64 + kk;
      As[kk][m] = ldf(A, aoff);
      int col = bcn*64 + m;
      Bs[kk][m] = B[(long)col*KD + kc*64 + kk];
    }
    __syncthreads();
    #pragma unroll 8
    for (int kk = 0; kk < 64; ++kk) {
      float a0 = As[kk][ty*4+0], a1 = As[kk][ty*4+1], a2 = As[kk][ty*4+2], a3 = As[kk][ty*4+3];
      float b0 = Bs[kk][tx*4+0], b1 = Bs[kk][tx*4+1], b2v = Bs[kk][tx*4+2], b3 = Bs[kk][tx*4+3];
      acc[0][0] += a0*b0; acc[0][1] += a0*b1; acc[0][2] += a0*b2v; acc[0][3] += a0*b3;
      acc[1][0] += a1*b0; acc[1][1] += a1*b1; acc[1][2] += a1*b2v; acc[1][3] += a1*b3;
      acc[2][0] += a2*b0; acc[2][1] += a2*b1; acc[2][2] += a2*b2v; acc[2][3] += a2*b3;
      acc[3][0] += a3*b0; acc[3][1] += a3*b1; acc[3][2] += a3*b2v; acc[3][3] += a3*b3;
    }
  }
  float bv[4];
  #pragma unroll
  for (int j = 0; j < 4; ++j) bv[j] = bias ? bias[bcn*64 + tx*4 + j] : 0.f;
  #pragma unroll
  for (int i = 0; i < 4; ++i) {
    long ro = (long)(rt*64 + ty*4 + i)*NC + bcn*64 + tx*4;
    #pragma unroll
    for (int j = 0; j < 4; ++j) stf(C, ro + j, acc[i][j] + bv[j]);
  }
}

// ---------------- GRU recurrence: one block (192 thr) per batch row ----------------
__global__ __launch_bounds__(192) void k_gru(
  const float* __restrict__ gi, const float* __restrict__ whh, const float* __restrict__ bhh,
  bf16* __restrict__ g_out, float* __restrict__ res_out, int layer)
{
  int n = blockIdx.x;
  int tid = threadIdx.x;
  int g = tid >> 6, o = tid & 63;
  __shared__ float h_lds[64];
  __shared__ float ghs[3][64];
  float w[64];
  #pragma unroll
  for (int k = 0; k < 64; ++k) w[k] = whh[(long)(g*64+o)*64 + k];
  float bh = bhh[g*64+o];
  if (tid < 64) h_lds[tid] = 0.f;
  __syncthreads();
  for (int t = 0; t < TT; ++t) {
    float s = bh;
    #pragma unroll
    for (int k = 0; k < 64; ++k) s += w[k]*h_lds[k];
    ghs[g][o] = s;
    __syncthreads();
    if (tid < 64) {
      const float* gib = gi + ((long)n*TT + t)*192;
      float ir = gib[o], iz = gib[64+o], inn = gib[128+o];
      float r = sgm(ir + ghs[0][o]);
      float z = sgm(iz + ghs[1][o]);
      float nn2 = tanhf(inn + r*ghs[2][o]);
      float hn = (1.f - z)*nn2 + z*h_lds[o];
      h_lds[o] = hn;
      if (layer == 0) g_out[((long)t*NN + n)*64 + o] = f2b(hn);
      else if (t == TT-1) res_out[(long)n*64 + o] = lk(hn);
    }
    __syncthreads();
  }
}

// ---------------- dynamic attention v2 ----------------
// Phase A unchanged arithmetic (np-exact scores via 4-lane seq mul/add, pairwise
// mean, mask, softmax) but float4 LDS traffic (stride 36, 16B-aligned).
// Phase B (P@V, bf16-tolerant) rewritten with mfma_f32_16x16x32_bf16:
//   P[16][512] bf16 in LDS (stride 520), V transposed vT[32][520] bf16.
//   4 waves: {col-tile nh = w&1} x {K-half kh = w>>1}, 8 MFMA each; partial
//   reduction through small LDS buffer; accumulate into resid.
// LDS 60928 -> 54400 B => 3 blocks/CU (grid 640 fully co-resident).
#define MULADD4(QV, KV) \
  v0 = __fadd_rn(v0, __fmul_rn((QV).x, (KV).x)); \
  v1 = __fadd_rn(v1, __fmul_rn((QV).y, (KV).y)); \
  v2 = __fadd_rn(v2, __fmul_rn((QV).z, (KV).z)); \
  v3 = __fadd_rn(v3, __fmul_rn((QV).w, (KV).w));

__global__ __launch_bounds__(256, 3) void k_attn_dyn(
  const float* __restrict__ qkx, const bf16* __restrict__ vvc,
  float* __restrict__ attn_out, float* __restrict__ resid, int tc)
{
  // region A [0,33280): sc f32[16][520] (phase A) | vT bf16[32][520] (phase B)
  // region B [33280,54016): kt f32[128][36] + qtl f32[16][36] (phase A)
  //                          | p_lds bf16[16][520] + red f32[2][272] (phase B)
  // means [54016,54080), part [54080,54400)
  __shared__ __align__(16) char smem[54400];
  float* sc    = (float*)smem;                     // [16][520]
  bf16*  vT    = (bf16*)smem;                      // [32][520]
  float* kt    = (float*)(smem + 33280);           // [128][36]
  bf16*  p_lds = (bf16*)(smem + 33280);            // [16][520]
  float* red   = (float*)(smem + 49920);           // [2][16*17]
  float* qtl   = (float*)(smem + 51712);           // [16][36]
  float* means = (float*)(smem + 54016);           // [16]
  float* part  = (float*)(smem + 54080);           // [16][5]

  int qt = blockIdx.x, h = blockIdx.y, lt = blockIdx.z;
  int gt = tc*TCH + lt;
  int tid = threadIdx.x, tx = tid & 31, grp = tid >> 5;
  int qbase = grp*2;
  int qce = h*32, kce = 64 + h*32;

  // stage q tile [16][32] (float4)
  for (int i = tid; i < 128; i += 256) {
    int row = i >> 3, jj = (i & 7) << 2;
    *(float4*)(qtl + row*36 + jj) =
      *(const float4*)(qkx + ((long)(lt*NN + qt*16 + row))*128 + qce + jj);
  }

  float S[2][16];
  for (int p = 0; p < 4; ++p) {
    __syncthreads();
    for (int i = tid; i < 1024; i += 256) {
      int row = i >> 3, jj = (i & 7) << 2;
      *(float4*)(kt + row*36 + jj) =
        *(const float4*)(qkx + ((long)(lt*NN + p*128 + row))*128 + kce + jj);
    }
    __syncthreads();
    #pragma unroll
    for (int ii = 0; ii < 4; ++ii) {
      int m = tx + 32*ii;
      const float4* kr4 = (const float4*)(kt + m*36);
      float4 k0 = kr4[0], k1 = kr4[1], k2 = kr4[2], k3 = kr4[3];
      float4 k4 = kr4[4], k5 = kr4[5], k6 = kr4[6], k7 = kr4[7];
      #pragma unroll
      for (int qi = 0; qi < 2; ++qi) {
        const float4* qr4 = (const float4*)(qtl + (qbase+qi)*36);
        // numpy einsum baseline-SIMD emulation: 4 lanes, sequential unfused
        // mul+add per lane over d = l, l+4, ..., l+28; SSE3 hadd tree at end.
        float v0 = 0.f, v1 = 0.f, v2 = 0.f, v3 = 0.f;
        float4 qv;
        qv = qr4[0]; MULADD4(qv, k0);
        qv = qr4[1]; MULADD4(qv, k1);
        qv = qr4[2]; MULADD4(qv, k2);
        qv = qr4[3]; MULADD4(qv, k3);
        qv = qr4[4]; MULADD4(qv, k4);
        qv = qr4[5]; MULADD4(qv, k5);
        qv = qr4[6]; MULADD4(qv, k6);
        qv = qr4[7]; MULADD4(qv, k7);
        float s = __fadd_rn(__fadd_rn(v0, v1), __fadd_rn(v2, v3));
        s = s * 0.125f;   // exact pow2 scale
        S[qi][p*4+ii] = s;
        sc[(qbase+qi)*520 + p*128 + m] = s;
      }
    }
  }
  __syncthreads();
  // numpy pairwise mean over 512 (per row): 4x128-base-blocks then tree
  if (tid < 64) {
    int row = tid >> 2, b = tid & 3;
    const float* a = sc + row*520 + b*128;
    float r0 = a[0], r1 = a[1], r2 = a[2], r3 = a[3];
    float r4 = a[4], r5 = a[5], r6 = a[6], r7 = a[7];
    for (int i = 8; i < 128; i += 8) {
      r0 = __fadd_rn(r0, a[i+0]); r1 = __fadd_rn(r1, a[i+1]);
      r2 = __fadd_rn(r2, a[i+2]); r3 = __fadd_rn(r3, a[i+3]);
      r4 = __fadd_rn(r4, a[i+4]); r5 = __fadd_rn(r5, a[i+5]);
      r6 = __fadd_rn(r6, a[i+6]); r7 = __fadd_rn(r7, a[i+7]);
    }
    part[row*5 + b] = __fadd_rn(
        __fadd_rn(__fadd_rn(r0, r1), __fadd_rn(r2, r3)),
        __fadd_rn(__fadd_rn(r4, r5), __fadd_rn(r6, r7)));
  }
  __syncthreads();
  if (tid < 16) {
    float s = __fadd_rn(__fadd_rn(part[tid*5+0], part[tid*5+1]),
                        __fadd_rn(part[tid*5+2], part[tid*5+3]));
    means[tid] = s * (1.f/512.f);   // exact pow2 divide
  }
  __syncthreads();

  long obase = ((long)(gt*2 + h))*NN*NN;
  #pragma unroll
  for (int qi = 0; qi < 2; ++qi) {
    float mn = means[qbase + qi];
    unsigned kmask = 0; float lm = -INFINITY;
    #pragma unroll
    for (int ig = 0; ig < 16; ++ig) {
      if (S[qi][ig] >= mn) { kmask |= (1u << ig); lm = fmaxf(lm, S[qi][ig]); }
    }
    #pragma unroll
    for (int mk = 1; mk < 32; mk <<= 1) lm = fmaxf(lm, __shfl_xor(lm, mk, 64));
    float e[16]; float se = 0.f;
    #pragma unroll
    for (int ig = 0; ig < 16; ++ig) {
      e[ig] = ((kmask >> ig) & 1u) ? __expf(S[qi][ig] - lm) : 0.f;
      se += e[ig];
    }
    #pragma unroll
    for (int mk = 1; mk < 32; mk <<= 1) se += __shfl_xor(se, mk, 64);
    float inv = 1.f/se;
    float* rowp = attn_out + obase + (long)(qt*16 + qbase + qi)*NN;
    bf16* prow = p_lds + (qbase + qi)*520;
    #pragma unroll
    for (int ig = 0; ig < 16; ++ig) {
      float pr = e[ig]*inv;
      rowp[tx + 32*ig] = pr;
      prow[tx + 32*ig] = f2b(pr);
    }
  }

  // stage V transposed: vT[col][k], paired rows packed into dword writes
  for (int i = tid; i < 2048; i += 256) {
    int m2 = (i & 255) << 1;          // k rows m2, m2+1
    int cc = (i >> 8) << 2;           // col base
    const bf16* gp = vvc + ((long)(lt*NN + m2))*128 + qce + cc;
    ushort4 a = *(const ushort4*)(gp);
    ushort4 b = *(const ushort4*)(gp + 128);
    *(unsigned*)(vT + (cc+0)*520 + m2) = (unsigned)a.x | ((unsigned)b.x << 16);
    *(unsigned*)(vT + (cc+1)*520 + m2) = (unsigned)a.y | ((unsigned)b.y << 16);
    *(unsigned*)(vT + (cc+2)*520 + m2) = (unsigned)a.z | ((unsigned)b.z << 16);
    *(unsigned*)(vT + (cc+3)*520 + m2) = (unsigned)a.w | ((unsigned)b.w << 16);
  }
  __syncthreads();

  // phase B: O = P @ V via MFMA. wave w: col-tile nh=w&1, K-half kh=w>>1
  {
    int w = tid >> 6, l = tid & 63;
    int nh = w & 1, kh = w >> 1;
    int arow = l & 15, kgrp = l >> 4;
    facc4 acc = {0.f, 0.f, 0.f, 0.f};
    const bf16* pa = p_lds + arow*520 + kh*256 + kgrp*8;
    const bf16* pb = vT + (nh*16 + arow)*520 + kh*256 + kgrp*8;
    #pragma unroll
    for (int ks = 0; ks < 8; ++ks) {
      bfrag8 av = *(const bfrag8*)(pa + ks*32);
      bfrag8 bv = *(const bfrag8*)(pb + ks*32);
      acc = __builtin_amdgcn_mfma_f32_16x16x32_bf16(av, bv, acc, 0, 0, 0);
    }
    if (w >= 2) {
      #pragma unroll
      for (int r = 0; r < 4; ++r)
        red[nh*272 + (kgrp*4 + r)*17 + arow] = acc[r];
    }
    __syncthreads();
    if (w < 2) {
      long rb = ((long)gt*NN + qt*16)*64 + h*32 + nh*16 + arow;
      #pragma unroll
      for (int r = 0; r < 4; ++r) {
        int row = kgrp*4 + r;
        resid[rb + (long)row*64] += acc[r] + red[nh*272 + row*17 + arow];
      }
    }
  }
}

// ---------------- static attention (fp32, adjacency bitmask) ----------------
__global__ __launch_bounds__(256) void k_attn_st(
  const float* __restrict__ qkc, const bf16* __restrict__ vvc,
  const unsigned int* __restrict__ msk, float* __restrict__ resid, int tc)
{
  __shared__ float smem[12544];
  float* q_lds = smem;                          // [32][65]
  float* kc    = smem + 32*65;                  // [128][65]
  bf16*  p_lds = (bf16*)smem;                   // [32][522] alias
  bf16*  v_lds = (bf16*)((char*)smem + 33408);  // [128][64]

  int qt = blockIdx.x, lt = blockIdx.z;
  int gt = tc*TCH + lt;
  int tid = threadIdx.x;
  int tx = tid & 31, grp = tid >> 5;
  int qbase = grp*4;

  for (int idx = tid; idx < 32*64; idx += 256) {
    int row = idx >> 6, j = idx & 63;
    q_lds[row*65 + j] = qkc[((long)lt*NN + qt*32 + row)*128 + j];
  }
  float S[4][16];
  #pragma unroll
  for (int a = 0; a < 4; ++a)
    #pragma unroll
    for (int b = 0; b < 16; ++b) S[a][b] = 0.f;

  for (int p = 0; p < 4; ++p) {
    __syncthreads();
    for (int idx = tid; idx < 128*64; idx += 256) {
      int row = idx >> 6, j = idx & 63;
      kc[row*65 + j] = qkc[((long)lt*NN + p*128 + row)*128 + 64 + j];
    }
    __syncthreads();
    for (int j = 0; j < 64; ++j) {
      float qv[4];
      #pragma unroll
      for (int qi = 0; qi < 4; ++qi) qv[qi] = q_lds[(qbase+qi)*65 + j];
      #pragma unroll
      for (int ii = 0; ii < 4; ++ii) {
        float kv = kc[(tx + 32*ii)*65 + j];
        #pragma unroll
        for (int qi = 0; qi < 4; ++qi) S[qi][p*4 + ii] += qv[qi]*kv;
      }
    }
  }
  #pragma unroll
  for (int qi = 0; qi < 4; ++qi)
    #pragma unroll
    for (int ig = 0; ig < 16; ++ig) S[qi][ig] *= SCALEV;

  #pragma unroll
  for (int qi = 0; qi < 4; ++qi) {
    float lm = -INFINITY;
    #pragma unroll
    for (int ig = 0; ig < 16; ++ig) {
      bool keep = ((msk[(qt*32 + qbase + qi)*16 + ig] >> tx) & 1u) != 0u;
      float v = keep ? S[qi][ig] : NEGV;
      S[qi][ig] = v;
      lm = fmaxf(lm, v);
    }
    #pragma unroll
    for (int mk = 1; mk < 32; mk <<= 1) lm = fmaxf(lm, __shfl_xor(lm, mk, 64));
    float se = 0.f;
    #pragma unroll
    for (int ig = 0; ig < 16; ++ig) {
      float ev = __expf(S[qi][ig] - lm);
      S[qi][ig] = ev;
      se += ev;
    }
    #pragma unroll
    for (int mk = 1; mk < 32; mk <<= 1) se += __shfl_xor(se, mk, 64);
    float inv = 1.f / se;
    #pragma unroll
    for (int ig = 0; ig < 16; ++ig) S[qi][ig] *= inv;
  }

  __syncthreads();
  #pragma unroll
  for (int qi = 0; qi < 4; ++qi)
    #pragma unroll
    for (int ig = 0; ig < 16; ++ig)
      p_lds[(qbase+qi)*522 + tx + 32*ig] = f2b(S[qi][ig]);

  int q = tid >> 3, cb = (tid & 7)*8;
  float acc[8];
  #pragma unroll
  for (int j = 0; j < 8; ++j) acc[j] = 0.f;
  for (int p = 0; p < 4; ++p) {
    __syncthreads();
    for (int idx = tid; idx < 128*64; idx += 256) {
      int row = idx >> 6, cc = idx & 63;
      v_lds[row*64 + cc] = vvc[((long)lt*NN + p*128 + row)*128 + 64 + cc];
    }
    __syncthreads();
    for (int m = 0; m < 128; ++m) {
      float pv = b2f(p_lds[q*522 + p*128 + m]);
      #pragma unroll
      for (int j = 0; j < 8; ++j) acc[j] += pv * b2f(v_lds[m*64 + cb + j]);
    }
  }
  long rbase = ((long)gt*NN + qt*32 + q)*64 + cb;
  #pragma unroll
  for (int j = 0; j < 8; ++j) resid[rbase + j] += acc[j];
}

// ---------------- LN1 ----------------
__global__ __launch_bounds__(256) void k_ln1(
  const float* __restrict__ resid, const float* __restrict__ gw, const float* __restrict__ bw,
  float* __restrict__ ln1o)
{
  int lane = threadIdx.x & 63;
  long r = (long)blockIdx.x*4 + (threadIdx.x >> 6);
  long base = r*64 + lane;
  float v = resid[base];
  float m = wsum64(v)*(1.f/64.f);
  float d = v - m;
  float var = wsum64(d*d)*(1.f/64.f);
  ln1o[base] = d*rsqrtf(var + 1e-5f)*gw[lane] + bw[lane];
}

// ---------------- LN2 + leaky + PE -> src ----------------
__global__ __launch_bounds__(256) void k_ln2_src(
  const float* __restrict__ mlpo, const float* __restrict__ resid,
  const float* __restrict__ gw, const float* __restrict__ bw,
  float* __restrict__ src)
{
  int lane = threadIdx.x & 63;
  long r = (long)blockIdx.x*4 + (threadIdx.x >> 6);
  long base = r*64 + lane;
  float v = mlpo[base] + resid[base];
  float m = wsum64(v)*(1.f/64.f);
  float d = v - m;
  float var = wsum64(d*d)*(1.f/64.f);
  float y = d*rsqrtf(var + 1e-5f)*gw[lane] + bw[lane];
  y = lk(y);
  float tf = (float)(r / NN);
  float dv = __expf(-(float)(lane & ~1) * 0.14391156831212787f);
  float pe = (lane & 1) ? cosf(tf*dv) : sinf(tf*dv);
  src[base] = y + pe;
}

// ---------------- head ----------------
__global__ __launch_bounds__(64) void k_head(
  const bf16* __restrict__ mqkv, const float* __restrict__ rts,
  const float* __restrict__ mow, const float* __restrict__ mob,
  const float* __restrict__ xsw, const float* __restrict__ xtw, const float* __restrict__ xtb,
  const float* __restrict__ hw, const float* __restrict__ hb,
  const float* __restrict__ linw, const float* __restrict__ linb,
  float* __restrict__ out)
{
  int n = blockIdx.x, o = threadIdx.x;
  __shared__ float ps[TT];
  __shared__ float buf[64], buf2[64];
  float mq = b2f(mqkv[((long)(TT-1)*NN + n)*192 + o]);
  for (int s = 0; s < TT; ++s) {
    float v = mq * b2f(mqkv[((long)s*NN + n)*192 + 64 + o]);
    v = wsum64(v);
    if (o == 0) ps[s] = v * SCALEV;
  }
  __syncthreads();
  float x = (o < TT) ? ps[o] : -INFINITY;
  float mx = wmax64(x);
  float e = (o < TT) ? __expf(x - mx) : 0.f;
  float se = wsum64(e);
  if (o < TT) ps[o] = e / se;
  __syncthreads();
  float acc = 0.f;
  for (int s = 0; s < TT; ++s) acc += ps[s]*b2f(mqkv[((long)s*NN + n)*192 + 128 + o]);
  buf[o] = acc;
  __syncthreads();
  float acc2 = mob[o];
  for (int k = 0; k < 64; ++k) acc2 += buf[k]*mow[o*64 + k];
  float m2 = wsum64(acc2)*(1.f/64.f);
  float d2 = acc2 - m2;
  float var2 = wsum64(d2*d2)*(1.f/64.f);
  float a = d2*rsqrtf(var2 + 1e-5f);
  float rt = rts[(long)n*64 + o];
  __syncthreads();
  buf[o] = a; buf2[o] = rt;
  __syncthreads();
  float pre = xtb[o];
  for (int k = 0; k < 64; ++k) pre += buf[k]*xsw[o*64 + k] + buf2[k]*xtw[o*64 + k];
  float zg = sgm(pre);
  float u = zg*a + (1.f - zg)*rt;
  __syncthreads();
  buf[o] = u;
  __syncthreads();
  float f = hb[o];
  for (int k = 0; k < 64; ++k) f += buf[k]*hw[o*64 + k];
  f = lk(f);
  float tot = wsum64(f * linw[o]);
  if (o == 0) out[n] = tot + linb[0];
}

// =======================================================================
extern "C" void kernel_launch(void* const* d_in, const int* in_sizes, int n_in,
                              void* d_out, int out_size, void* d_ws, size_t ws_size,
                              hipStream_t stream)
{
  const float* x    = (const float*)d_in[0];
  const int*   ei   = (const int*)  d_in[1];
  const float* fcw  = (const float*)d_in[2];
  const float* fcb  = (const float*)d_in[3];
  const float* wih0 = (const float*)d_in[4];
  const float* whh0 = (const float*)d_in[5];
  const float* bih0 = (const float*)d_in[6];
  const float* bhh0 = (const float*)d_in[7];
  const float* wih1 = (const float*)d_in[8];
  const float* whh1 = (const float*)d_in[9];
  const float* bih1 = (const float*)d_in[10];
  const float* bhh1 = (const float*)d_in[11];
  const float* dmqw = (const float*)d_in[12];
  const float* dmkw = (const float*)d_in[13];
  const float* dmvw = (const float*)d_in[14];
  const float* dmvb = (const float*)d_in[15];
  const float* ssqw = (const float*)d_in[16];
  const float* sskw = (const float*)d_in[17];
  const float* ssvw = (const float*)d_in[18];
  const float* ssvb = (const float*)d_in[19];
  const float* ln1g = (const float*)d_in[20];
  const float* ln1b = (const float*)d_in[21];
  const float* ln2g = (const float*)d_in[22];
  const float* ln2b = (const float*)d_in[23];
  const float* mw1  = (const float*)d_in[24];
  const float* mb1  = (const float*)d_in[25];
  const float* mw2  = (const float*)d_in[26];
  const float* mb2  = (const float*)d_in[27];
  const float* mhw  = (const float*)d_in[28];
  const float* mhb  = (const float*)d_in[29];
  const float* mow  = (const float*)d_in[30];
  const float* mob  = (const float*)d_in[31];
  const float* gxsw = (const float*)d_in[32];
  const float* gxtw = (const float*)d_in[33];
  const float* gxtb = (const float*)d_in[34];
  const float* ghw  = (const float*)d_in[35];
  const float* ghb  = (const float*)d_in[36];
  const float* linw = (const float*)d_in[37];
  const float* linb = (const float*)d_in[38];

  // ---- workspace layout (~43.6 MB envelope, unchanged) ----
  char* base = (char*)d_ws;
  float*  xs    = (float*)(base);                 // xs f32; later mlpo f32
  char*   Rb    = base + 7864320;                 // shared region:
  float*  qkc   = (float*)Rb;                     //   per-chunk qs|ks f32 (2.62MB)
  bf16*   vvc   = (bf16*)(Rb + 2621440);          //   per-chunk v|vs bf16 (1.31MB)
  float*  qkx   = (float*)(Rb + 3932160);         //   per-chunk exact q|k f32 (2.62MB)
  float*  mlph  = (float*)Rb;                     //   later: mlp hidden f32
  bf16*   mqkv  = (bf16*)Rb;                      //   later: mha qkv bf16
  bf16*   g0    = (bf16*)(base + 23592960);
  float*  resid = (float*)(base + 27525120);
  float*  ln1o  = (float*)(base + 35389440);
  float*  rts   = (float*)(base + 43253760);
  unsigned int* msk = (unsigned int*)(base + 43384832);
  float*  Wc    = (float*)(base + 43417600);      // 4*4096 f32 (qs|ks|v|vs)
  float*  bcV   = (float*)(base + 43483136);      // 128 f32
  float*  Wqk   = (float*)(base + 43483648);      // 128*64 f32 (q|k)
  float*  mlpo  = xs;
  float*  src   = ln1o;
  float*  outb  = (float*)d_out;
  float*  attn  = outb + 512;
  // gi staged in d_out's attn region — dead before k_attn_dyn writes probs
  float*  gi    = (float*)((char*)d_out + 2048);

  k_zero_u32<<<dim3(32), 256, 0, stream>>>(msk, 512*16);
  k_scatter_bits<<<dim3(32), 256, 0, stream>>>(ei, msk);
  k_pack<<<dim3(97), 256, 0, stream>>>(ssqw, sskw, dmvw, ssvw, dmvb, ssvb, dmqw, dmkw, Wc, bcV, Wqk);
  k_fcin<<<dim3(TN*64/256), 256, 0, stream>>>(x, fcw, fcb, xs, resid);
  // GRU layer 0
  k_gemm<float,float><<<dim3(480, 3), 256, 0, stream>>>(xs, wih0, bih0, gi, 64, 192, 1);
  k_gru<<<dim3(NN), 192, 0, stream>>>(gi, whh0, bhh0, g0, nullptr, 0);
  // GRU layer 1
  k_gemm<bf16,float><<<dim3(480, 3), 256, 0, stream>>>(g0, wih1, bih1, gi, 64, 192, 1);
  k_gru<<<dim3(NN), 192, 0, stream>>>(gi, whh1, bhh1, nullptr, rts, 1);
  // attention in 6 t-chunks
  for (int tc = 0; tc < NCHK; ++tc) {
    const float* xsc = xs + (size_t)tc*TCH*NN*64;
    k_qkx<<<dim3(80, 2), 256, 0, stream>>>(xsc, Wqk, qkx);
    k_gemm<float,float><<<dim3(80, 2), 256, 0, stream>>>(xsc, Wc, nullptr, qkc, 64, 128, 0);
    k_gemm<float,bf16 ><<<dim3(80, 2), 256, 0, stream>>>(xsc, Wc + 2*4096, bcV, vvc, 64, 128, 0);
    k_attn_dyn<<<dim3(32, 2, TCH), 256, 0, stream>>>(qkx, vvc, attn, resid, tc);
    k_attn_st <<<dim3(16, 1, TCH), 256, 0, stream>>>(qkc, vvc, msk, resid, tc);
  }
  // LN1 -> MLP -> LN2+PE
  k_ln1<<<dim3(TN/4), 256, 0, stream>>>(resid, ln1g, ln1b, ln1o);
  k_gemm<float,float><<<dim3(480, 2), 256, 0, stream>>>(ln1o, mw1, mb1, mlph, 64, 128, 0);
  k_gemm<float,float><<<dim3(480, 1), 256, 0, stream>>>(mlph, mw2, mb2, mlpo, 128, 64, 0);
  k_ln2_src<<<dim3(TN/4), 256, 0, stream>>>(mlpo, resid, ln2g, ln2b, src);
  // mha in-projection + head
  k_gemm<float,bf16 ><<<dim3(480, 3), 256, 0, stream>>>(src, mhw, mhb, mqkv, 64, 192, 0);
  k_head<<<dim3(NN), 64, 0, stream>>>(mqkv, rts, mow, mob, gxsw, gxtw, gxtb, ghw, ghb, linw, linb, outb);
}

// Round 2
// 1140.691 us; speedup vs baseline: 1.2679x; 1.1397x over previous
//
#include <hip/hip_runtime.h>
#include <hip/hip_bf16.h>

#define NN 512
#define TT 60
#define DFF 6
#define EE 8192
#define TN (TT*NN)
#define TCH 10          // t-chunk size
#define NCHK 6          // number of t-chunks
#define SCALEV 0.125f
#define NEGV -1.0e10f

typedef __hip_bfloat16 bf16;
using bfrag8 = __attribute__((ext_vector_type(8))) short;   // 8 bf16 (4 VGPRs)
using facc4  = __attribute__((ext_vector_type(4))) float;   // 4 f32 acc

__device__ __forceinline__ float b2f(bf16 v){ return __bfloat162float(v); }
__device__ __forceinline__ bf16 f2b(float v){ return __float2bfloat16(v); }
__device__ __forceinline__ float lk(float x){ return x >= 0.f ? x : 0.01f*x; }
__device__ __forceinline__ float sgm(float x){ return 1.f/(1.f+__expf(-x)); }

__device__ __forceinline__ float ldf(const float* p, long i){ return p[i]; }
__device__ __forceinline__ float ldf(const bf16* p, long i){ return b2f(p[i]); }
__device__ __forceinline__ void stf(float* p, long i, float v){ p[i] = v; }
__device__ __forceinline__ void stf(bf16* p, long i, float v){ p[i] = f2b(v); }

__device__ __forceinline__ float wsum64(float v){
  #pragma unroll
  for (int off = 32; off; off >>= 1) v += __shfl_xor(v, off, 64);
  return v;
}
__device__ __forceinline__ float wmax64(float v){
  #pragma unroll
  for (int off = 32; off; off >>= 1) v = fmaxf(v, __shfl_xor(v, off, 64));
  return v;
}

// ---------------- adjacency bitmask ----------------
__global__ __launch_bounds__(256) void k_zero_u32(unsigned int* __restrict__ p, int n){
  int i = blockIdx.x*256 + threadIdx.x;
  if (i < n) p[i] = 0u;
}
__global__ __launch_bounds__(256) void k_scatter_bits(const int* __restrict__ ei, unsigned int* __restrict__ msk){
  int e = blockIdx.x*256 + threadIdx.x;
  if (e < EE) {
    int u = ei[e], v = ei[EE + e];
    atomicOr(&msk[u*16 + (v >> 5)], 1u << (v & 31));
  }
}

// ---------------- pack: Wc f32 = qs|ks|v|vs ; bcV = vb|vsb ; Wqk f32 = q|k ----------------
__global__ __launch_bounds__(256) void k_pack(
  const float* __restrict__ qsw, const float* __restrict__ ksw,
  const float* __restrict__ vw, const float* __restrict__ vsw,
  const float* __restrict__ vb, const float* __restrict__ vsb,
  const float* __restrict__ qw, const float* __restrict__ kw,
  float* __restrict__ Wc, float* __restrict__ bcV, float* __restrict__ Wqk)
{
  int idx = blockIdx.x*256 + threadIdx.x;
  if (idx < 4*4096) {
    int which = idx >> 12, rem = idx & 4095;
    const float* s = (which==0)?qsw:(which==1)?ksw:(which==2)?vw:vsw;
    Wc[idx] = s[rem];
  } else if (idx < 4*4096 + 128) {
    int o = idx - 4*4096;
    bcV[o] = (o < 64) ? vb[o] : vsb[o-64];
  } else if (idx < 4*4096 + 128 + 8192) {
    int i2 = idx - (4*4096 + 128);
    Wqk[i2] = (i2 < 4096) ? qw[i2] : kw[i2 - 4096];
  }
}

// ---------------- fc_in: np-exact fp32 (seq-FMA over k, bias added after) ----------------
__global__ __launch_bounds__(256) void k_fcin(
  const float* __restrict__ x, const float* __restrict__ w, const float* __restrict__ b,
  float* __restrict__ xs, float* __restrict__ resid)
{
  long idx = (long)blockIdx.x*256 + threadIdx.x;   // < TN*64
  int o = idx & 63;
  long r = idx >> 6;                // r = t*NN + n
  int t = (int)(r / NN), n = (int)(r % NN);
  const float* xr = x + ((long)n*TT + t)*DFF;
  const float* wr = w + o*DFF;
  float acc = 0.f;
  #pragma unroll
  for (int j = 0; j < DFF; ++j) acc = fmaf(xr[j], wr[j], acc);
  float h = __fadd_rn(acc, b[o]);
  xs[idx] = h;
  resid[idx] = h;
}

// ---------------- np-exact q|k projection (seq-FMA over k=0..63) ----------------
// qkx[rc][128] = h[rc] @ Wqk^T, rc chunk-local row; A = xs chunk base (row-major 64)
__global__ __launch_bounds__(256) void k_qkx(
  const float* __restrict__ A, const float* __restrict__ Wqk, float* __restrict__ qkx)
{
  __shared__ float As[64][65];
  __shared__ float Bs[64][65];
  int rt = blockIdx.x, bcn = blockIdx.y;
  int tid = threadIdx.x;
  int tx = tid & 15, ty = tid >> 4;
  float acc[4][4] = {{0.f}};
  #pragma unroll
  for (int i = 0; i < 16; ++i) {
    int idx = i*256 + tid;
    int m = idx >> 6, kk = idx & 63;
    As[kk][m] = A[(long)(rt*64 + m)*64 + kk];
    Bs[kk][m] = Wqk[(long)(bcn*64 + m)*64 + kk];
  }
  __syncthreads();
  for (int kk = 0; kk < 64; ++kk) {
    float a0 = As[kk][ty*4+0], a1 = As[kk][ty*4+1], a2 = As[kk][ty*4+2], a3 = As[kk][ty*4+3];
    float b0 = Bs[kk][tx*4+0], b1 = Bs[kk][tx*4+1], b2v = Bs[kk][tx*4+2], b3 = Bs[kk][tx*4+3];
    acc[0][0] = fmaf(a0,b0,acc[0][0]); acc[0][1] = fmaf(a0,b1,acc[0][1]); acc[0][2] = fmaf(a0,b2v,acc[0][2]); acc[0][3] = fmaf(a0,b3,acc[0][3]);
    acc[1][0] = fmaf(a1,b0,acc[1][0]); acc[1][1] = fmaf(a1,b1,acc[1][1]); acc[1][2] = fmaf(a1,b2v,acc[1][2]); acc[1][3] = fmaf(a1,b3,acc[1][3]);
    acc[2][0] = fmaf(a2,b0,acc[2][0]); acc[2][1] = fmaf(a2,b1,acc[2][1]); acc[2][2] = fmaf(a2,b2v,acc[2][2]); acc[2][3] = fmaf(a2,b3,acc[2][3]);
    acc[3][0] = fmaf(a3,b0,acc[3][0]); acc[3][1] = fmaf(a3,b1,acc[3][1]); acc[3][2] = fmaf(a3,b2v,acc[3][2]); acc[3][3] = fmaf(a3,b3,acc[3][3]);
  }
  #pragma unroll
  for (int i = 0; i < 4; ++i) {
    long ro = (long)(rt*64 + ty*4 + i)*128 + bcn*64 + tx*4;
    #pragma unroll
    for (int j = 0; j < 4; ++j) qkx[ro + j] = acc[i][j];
  }
}

// ---------------- generic projection GEMM (fp32, tolerant paths) ----------------
template<typename TA, typename TC>
__global__ __launch_bounds__(256) void k_gemm(
  const TA* __restrict__ A, const float* __restrict__ B, const float* __restrict__ bias,
  TC* __restrict__ C, int KD, int NC, int gather)
{
  __shared__ float As[64][65];
  __shared__ float Bs[64][65];
  int rt = blockIdx.x, bcn = blockIdx.y;
  int tid = threadIdx.x;
  int tx = tid & 15, ty = tid >> 4;
  float acc[4][4] = {{0.f}};
  int nch = KD >> 6;
  for (int kc = 0; kc < nch; ++kc) {
    __syncthreads();
    #pragma unroll
    for (int i = 0; i < 16; ++i) {
      int idx = i*256 + tid;
      int m = idx >> 6, kk = idx & 63;
      long aoff;
      int r = rt*64 + m;
      if (gather) { int n = r / TT, t = r - n*TT; aoff = ((long)t*NN + n)*64 + kk; }
      else aoff = (long)r*KD + kc*64 + kk;
      As[kk][m] = ldf(A, aoff);
      int col = bcn*64 + m;
      Bs[kk][m] = B[(long)col*KD + kc*64 + kk];
    }
    __syncthreads();
    #pragma unroll 8
    for (int kk = 0; kk < 64; ++kk) {
      float a0 = As[kk][ty*4+0], a1 = As[kk][ty*4+1], a2 = As[kk][ty*4+2], a3 = As[kk][ty*4+3];
      float b0 = Bs[kk][tx*4+0], b1 = Bs[kk][tx*4+1], b2v = Bs[kk][tx*4+2], b3 = Bs[kk][tx*4+3];
      acc[0][0] += a0*b0; acc[0][1] += a0*b1; acc[0][2] += a0*b2v; acc[0][3] += a0*b3;
      acc[1][0] += a1*b0; acc[1][1] += a1*b1; acc[1][2] += a1*b2v; acc[1][3] += a1*b3;
      acc[2][0] += a2*b0; acc[2][1] += a2*b1; acc[2][2] += a2*b2v; acc[2][3] += a2*b3;
      acc[3][0] += a3*b0; acc[3][1] += a3*b1; acc[3][2] += a3*b2v; acc[3][3] += a3*b3;
    }
  }
  float bv[4];
  #pragma unroll
  for (int j = 0; j < 4; ++j) bv[j] = bias ? bias[bcn*64 + tx*4 + j] : 0.f;
  #pragma unroll
  for (int i = 0; i < 4; ++i) {
    long ro = (long)(rt*64 + ty*4 + i)*NC + bcn*64 + tx*4;
    #pragma unroll
    for (int j = 0; j < 4; ++j) stf(C, ro + j, acc[i][j] + bv[j]);
  }
}

// ---------------- GRU recurrence: one block (192 thr) per batch row ----------------
__global__ __launch_bounds__(192) void k_gru(
  const float* __restrict__ gi, const float* __restrict__ whh, const float* __restrict__ bhh,
  bf16* __restrict__ g_out, float* __restrict__ res_out, int layer)
{
  int n = blockIdx.x;
  int tid = threadIdx.x;
  int g = tid >> 6, o = tid & 63;
  __shared__ float h_lds[64];
  __shared__ float ghs[3][64];
  float w[64];
  #pragma unroll
  for (int k = 0; k < 64; ++k) w[k] = whh[(long)(g*64+o)*64 + k];
  float bh = bhh[g*64+o];
  if (tid < 64) h_lds[tid] = 0.f;
  __syncthreads();
  for (int t = 0; t < TT; ++t) {
    float s = bh;
    #pragma unroll
    for (int k = 0; k < 64; ++k) s += w[k]*h_lds[k];
    ghs[g][o] = s;
    __syncthreads();
    if (tid < 64) {
      const float* gib = gi + ((long)n*TT + t)*192;
      float ir = gib[o], iz = gib[64+o], inn = gib[128+o];
      float r = sgm(ir + ghs[0][o]);
      float z = sgm(iz + ghs[1][o]);
      float nn2 = tanhf(inn + r*ghs[2][o]);
      float hn = (1.f - z)*nn2 + z*h_lds[o];
      h_lds[o] = hn;
      if (layer == 0) g_out[((long)t*NN + n)*64 + o] = f2b(hn);
      else if (t == TT-1) res_out[(long)n*64 + o] = lk(hn);
    }
    __syncthreads();
  }
}

// ---------------- dynamic attention v2 ----------------
// Phase A unchanged arithmetic (np-exact scores via 4-lane seq mul/add, pairwise
// mean, mask, softmax) but float4 LDS traffic (stride 36, 16B-aligned).
// Phase B (P@V, bf16-tolerant) rewritten with mfma_f32_16x16x32_bf16:
//   P[16][512] bf16 in LDS (stride 520), V transposed vT[32][520] bf16.
//   4 waves: {col-tile nh = w&1} x {K-half kh = w>>1}, 8 MFMA each; partial
//   reduction through small LDS buffer; accumulate into resid.
// LDS 60928 -> 54400 B => 3 blocks/CU (grid 640 fully co-resident).
#define MULADD4(QV, KV) \
  v0 = __fadd_rn(v0, __fmul_rn((QV).x, (KV).x)); \
  v1 = __fadd_rn(v1, __fmul_rn((QV).y, (KV).y)); \
  v2 = __fadd_rn(v2, __fmul_rn((QV).z, (KV).z)); \
  v3 = __fadd_rn(v3, __fmul_rn((QV).w, (KV).w));

__global__ __launch_bounds__(256, 3) void k_attn_dyn(
  const float* __restrict__ qkx, const bf16* __restrict__ vvc,
  float* __restrict__ attn_out, float* __restrict__ resid, int tc)
{
  // region A [0,33280): sc f32[16][520] (phase A) | vT bf16[32][520] (phase B)
  // region B [33280,54016): kt f32[128][36] + qtl f32[16][36] (phase A)
  //                          | p_lds bf16[16][520] + red f32[2][272] (phase B)
  // means [54016,54080), part [54080,54400)
  __shared__ __align__(16) char smem[54400];
  float* sc    = (float*)smem;                     // [16][520]
  bf16*  vT    = (bf16*)smem;                      // [32][520]
  float* kt    = (float*)(smem + 33280);           // [128][36]
  bf16*  p_lds = (bf16*)(smem + 33280);            // [16][520]
  float* red   = (float*)(smem + 49920);           // [2][16*17]
  float* qtl   = (float*)(smem + 51712);           // [16][36]
  float* means = (float*)(smem + 54016);           // [16]
  float* part  = (float*)(smem + 54080);           // [16][5]

  int qt = blockIdx.x, h = blockIdx.y, lt = blockIdx.z;
  int gt = tc*TCH + lt;
  int tid = threadIdx.x, tx = tid & 31, grp = tid >> 5;
  int qbase = grp*2;
  int qce = h*32, kce = 64 + h*32;

  // stage q tile [16][32] (float4)
  for (int i = tid; i < 128; i += 256) {
    int row = i >> 3, jj = (i & 7) << 2;
    *(float4*)(qtl + row*36 + jj) =
      *(const float4*)(qkx + ((long)(lt*NN + qt*16 + row))*128 + qce + jj);
  }

  float S[2][16];
  for (int p = 0; p < 4; ++p) {
    __syncthreads();
    for (int i = tid; i < 1024; i += 256) {
      int row = i >> 3, jj = (i & 7) << 2;
      *(float4*)(kt + row*36 + jj) =
        *(const float4*)(qkx + ((long)(lt*NN + p*128 + row))*128 + kce + jj);
    }
    __syncthreads();
    #pragma unroll
    for (int ii = 0; ii < 4; ++ii) {
      int m = tx + 32*ii;
      const float4* kr4 = (const float4*)(kt + m*36);
      float4 k0 = kr4[0], k1 = kr4[1], k2 = kr4[2], k3 = kr4[3];
      float4 k4 = kr4[4], k5 = kr4[5], k6 = kr4[6], k7 = kr4[7];
      #pragma unroll
      for (int qi = 0; qi < 2; ++qi) {
        const float4* qr4 = (const float4*)(qtl + (qbase+qi)*36);
        // numpy einsum baseline-SIMD emulation: 4 lanes, sequential unfused
        // mul+add per lane over d = l, l+4, ..., l+28; SSE3 hadd tree at end.
        float v0 = 0.f, v1 = 0.f, v2 = 0.f, v3 = 0.f;
        float4 qv;
        qv = qr4[0]; MULADD4(qv, k0);
        qv = qr4[1]; MULADD4(qv, k1);
        qv = qr4[2]; MULADD4(qv, k2);
        qv = qr4[3]; MULADD4(qv, k3);
        qv = qr4[4]; MULADD4(qv, k4);
        qv = qr4[5]; MULADD4(qv, k5);
        qv = qr4[6]; MULADD4(qv, k6);
        qv = qr4[7]; MULADD4(qv, k7);
        float s = __fadd_rn(__fadd_rn(v0, v1), __fadd_rn(v2, v3));
        s = s * 0.125f;   // exact pow2 scale
        S[qi][p*4+ii] = s;
        sc[(qbase+qi)*520 + p*128 + m] = s;
      }
    }
  }
  __syncthreads();
  // numpy pairwise mean over 512 (per row): 4x128-base-blocks then tree
  if (tid < 64) {
    int row = tid >> 2, b = tid & 3;
    const float* a = sc + row*520 + b*128;
    float r0 = a[0], r1 = a[1], r2 = a[2], r3 = a[3];
    float r4 = a[4], r5 = a[5], r6 = a[6], r7 = a[7];
    for (int i = 8; i < 128; i += 8) {
      r0 = __fadd_rn(r0, a[i+0]); r1 = __fadd_rn(r1, a[i+1]);
      r2 = __fadd_rn(r2, a[i+2]); r3 = __fadd_rn(r3, a[i+3]);
      r4 = __fadd_rn(r4, a[i+4]); r5 = __fadd_rn(r5, a[i+5]);
      r6 = __fadd_rn(r6, a[i+6]); r7 = __fadd_rn(r7, a[i+7]);
    }
    part[row*5 + b] = __fadd_rn(
        __fadd_rn(__fadd_rn(r0, r1), __fadd_rn(r2, r3)),
        __fadd_rn(__fadd_rn(r4, r5), __fadd_rn(r6, r7)));
  }
  __syncthreads();
  if (tid < 16) {
    float s = __fadd_rn(__fadd_rn(part[tid*5+0], part[tid*5+1]),
                        __fadd_rn(part[tid*5+2], part[tid*5+3]));
    means[tid] = s * (1.f/512.f);   // exact pow2 divide
  }
  __syncthreads();

  long obase = ((long)(gt*2 + h))*NN*NN;
  #pragma unroll
  for (int qi = 0; qi < 2; ++qi) {
    float mn = means[qbase + qi];
    unsigned kmask = 0; float lm = -INFINITY;
    #pragma unroll
    for (int ig = 0; ig < 16; ++ig) {
      if (S[qi][ig] >= mn) { kmask |= (1u << ig); lm = fmaxf(lm, S[qi][ig]); }
    }
    #pragma unroll
    for (int mk = 1; mk < 32; mk <<= 1) lm = fmaxf(lm, __shfl_xor(lm, mk, 64));
    float e[16]; float se = 0.f;
    #pragma unroll
    for (int ig = 0; ig < 16; ++ig) {
      e[ig] = ((kmask >> ig) & 1u) ? __expf(S[qi][ig] - lm) : 0.f;
      se += e[ig];
    }
    #pragma unroll
    for (int mk = 1; mk < 32; mk <<= 1) se += __shfl_xor(se, mk, 64);
    float inv = 1.f/se;
    float* rowp = attn_out + obase + (long)(qt*16 + qbase + qi)*NN;
    bf16* prow = p_lds + (qbase + qi)*520;
    #pragma unroll
    for (int ig = 0; ig < 16; ++ig) {
      float pr = e[ig]*inv;
      rowp[tx + 32*ig] = pr;
      prow[tx + 32*ig] = f2b(pr);
    }
  }

  // stage V transposed: vT[col][k], paired rows packed into dword writes
  for (int i = tid; i < 2048; i += 256) {
    int m2 = (i & 255) << 1;          // k rows m2, m2+1
    int cc = (i >> 8) << 2;           // col base
    const bf16* gp = vvc + ((long)(lt*NN + m2))*128 + qce + cc;
    ushort4 a = *(const ushort4*)(gp);
    ushort4 b = *(const ushort4*)(gp + 128);
    *(unsigned*)(vT + (cc+0)*520 + m2) = (unsigned)a.x | ((unsigned)b.x << 16);
    *(unsigned*)(vT + (cc+1)*520 + m2) = (unsigned)a.y | ((unsigned)b.y << 16);
    *(unsigned*)(vT + (cc+2)*520 + m2) = (unsigned)a.z | ((unsigned)b.z << 16);
    *(unsigned*)(vT + (cc+3)*520 + m2) = (unsigned)a.w | ((unsigned)b.w << 16);
  }
  __syncthreads();

  // phase B: O = P @ V via MFMA. wave w: col-tile nh=w&1, K-half kh=w>>1
  {
    int w = tid >> 6, l = tid & 63;
    int nh = w & 1, kh = w >> 1;
    int arow = l & 15, kgrp = l >> 4;
    facc4 acc = {0.f, 0.f, 0.f, 0.f};
    const bf16* pa = p_lds + arow*520 + kh*256 + kgrp*8;
    const bf16* pb = vT + (nh*16 + arow)*520 + kh*256 + kgrp*8;
    #pragma unroll
    for (int ks = 0; ks < 8; ++ks) {
      bfrag8 av = *(const bfrag8*)(pa + ks*32);
      bfrag8 bv = *(const bfrag8*)(pb + ks*32);
      acc = __builtin_amdgcn_mfma_f32_16x16x32_bf16(av, bv, acc, 0, 0, 0);
    }
    if (w >= 2) {
      #pragma unroll
      for (int r = 0; r < 4; ++r)
        red[nh*272 + (kgrp*4 + r)*17 + arow] = acc[r];
    }
    __syncthreads();
    if (w < 2) {
      long rb = ((long)gt*NN + qt*16)*64 + h*32 + nh*16 + arow;
      #pragma unroll
      for (int r = 0; r < 4; ++r) {
        int row = kgrp*4 + r;
        resid[rb + (long)row*64] += acc[r] + red[nh*272 + row*17 + arow];
      }
    }
  }
}

// ---------------- static attention v2 (fp32 scores, adjacency bitmask) ----------------
// 16 q-rows per block, grid (32,1,TCH) = 320 blocks (full CU coverage).
// Phase A: fp32 register-resident scores S[2][16] per thread; kc tile staged
//   with XOR swizzle (jc ^ ((m>>2)&3)) so the 32-row-strided ds_read_b128 is
//   <=2-way bank aliased; q reads are 2-way broadcast.
// Phase B: P[16][512] bf16 + V^T staged bf16 in two K-halves (aliases dead kc),
//   mfma_f32_16x16x32_bf16, wave w owns col-tile w (16 cols), acc across halves.
// LDS 51456 B => 3 blocks/CU.
__global__ __launch_bounds__(256, 3) void k_attn_st(
  const float* __restrict__ qkc, const bf16* __restrict__ vvc,
  const unsigned int* __restrict__ msk, float* __restrict__ resid, int tc)
{
  // R0 [0,34816): kc f32[128][68] swizzled (phase A) | vTh bf16[64][264] (phase B)
  // R1 [34816,51456): q f32[16][68] (phase A) | P bf16[16][520] (phase B)
  __shared__ __align__(16) char smem[51456];
  float* kc  = (float*)smem;                 // [128][68] f32 (swizzled float4 units)
  bf16*  vTh = (bf16*)smem;                  // [64][264] bf16 (K-half of V^T)
  float* qtl = (float*)(smem + 34816);       // [16][68] f32
  bf16*  P   = (bf16*)(smem + 34816);        // [16][520] bf16 (overlays qtl after use)

  int qt = blockIdx.x, lt = blockIdx.z;
  int gt = tc*TCH + lt;
  int tid = threadIdx.x;
  int tx = tid & 31, grp = tid >> 5;
  int qbase = grp*2;

  float4* q4 = (float4*)qtl;    // stride 17 float4
  float4* k4 = (float4*)kc;     // stride 17 float4

  // stage q tile [16][64] f32 (1 float4 per thread, coalesced)
  {
    int m = tid >> 4, jc = tid & 15;
    q4[m*17 + jc] = *(const float4*)(qkc + ((long)(lt*NN + qt*16 + m))*128 + jc*4);
  }

  float S[2][16];
  for (int p = 0; p < 4; ++p) {
    __syncthreads();
    // stage kc chunk [128][64] f32, XOR-swizzled float4 units
    for (int i = tid; i < 2048; i += 256) {
      int m = i >> 4, jc = i & 15;
      k4[m*17 + (jc ^ ((m >> 2) & 3))] =
        *(const float4*)(qkc + ((long)(lt*NN + p*128 + m))*128 + 64 + jc*4);
    }
    __syncthreads();
    float acc00 = 0.f, acc01 = 0.f, acc02 = 0.f, acc03 = 0.f;
    float acc10 = 0.f, acc11 = 0.f, acc12 = 0.f, acc13 = 0.f;
    #pragma unroll 4
    for (int jc = 0; jc < 16; ++jc) {
      float4 q0 = q4[(qbase+0)*17 + jc];
      float4 q1 = q4[(qbase+1)*17 + jc];
      float4 kv;
      int m0 = tx;
      kv = k4[m0*17 + (jc ^ ((m0 >> 2) & 3))];
      acc00 += q0.x*kv.x + q0.y*kv.y + q0.z*kv.z + q0.w*kv.w;
      acc10 += q1.x*kv.x + q1.y*kv.y + q1.z*kv.z + q1.w*kv.w;
      int m1 = tx + 32;
      kv = k4[m1*17 + (jc ^ ((m1 >> 2) & 3))];
      acc01 += q0.x*kv.x + q0.y*kv.y + q0.z*kv.z + q0.w*kv.w;
      acc11 += q1.x*kv.x + q1.y*kv.y + q1.z*kv.z + q1.w*kv.w;
      int m2 = tx + 64;
      kv = k4[m2*17 + (jc ^ ((m2 >> 2) & 3))];
      acc02 += q0.x*kv.x + q0.y*kv.y + q0.z*kv.z + q0.w*kv.w;
      acc12 += q1.x*kv.x + q1.y*kv.y + q1.z*kv.z + q1.w*kv.w;
      int m3 = tx + 96;
      kv = k4[m3*17 + (jc ^ ((m3 >> 2) & 3))];
      acc03 += q0.x*kv.x + q0.y*kv.y + q0.z*kv.z + q0.w*kv.w;
      acc13 += q1.x*kv.x + q1.y*kv.y + q1.z*kv.z + q1.w*kv.w;
    }
    S[0][p*4+0] = acc00; S[0][p*4+1] = acc01; S[0][p*4+2] = acc02; S[0][p*4+3] = acc03;
    S[1][p*4+0] = acc10; S[1][p*4+1] = acc11; S[1][p*4+2] = acc12; S[1][p*4+3] = acc13;
  }
  __syncthreads();   // kc + qtl dead after this point

  // scale + mask + softmax (fp32, register-resident)
  #pragma unroll
  for (int qi = 0; qi < 2; ++qi) {
    #pragma unroll
    for (int ig = 0; ig < 16; ++ig) S[qi][ig] *= SCALEV;
    float lm = -INFINITY;
    #pragma unroll
    for (int ig = 0; ig < 16; ++ig) {
      bool keep = ((msk[(qt*16 + qbase + qi)*16 + ig] >> tx) & 1u) != 0u;
      float v = keep ? S[qi][ig] : NEGV;
      S[qi][ig] = v;
      lm = fmaxf(lm, v);
    }
    #pragma unroll
    for (int mk = 1; mk < 32; mk <<= 1) lm = fmaxf(lm, __shfl_xor(lm, mk, 64));
    float se = 0.f;
    #pragma unroll
    for (int ig = 0; ig < 16; ++ig) {
      float ev = __expf(S[qi][ig] - lm);
      S[qi][ig] = ev;
      se += ev;
    }
    #pragma unroll
    for (int mk = 1; mk < 32; mk <<= 1) se += __shfl_xor(se, mk, 64);
    float inv = 1.f / se;
    bf16* prow = P + (qbase + qi)*520;
    #pragma unroll
    for (int ig = 0; ig < 16; ++ig)
      prow[tx + 32*ig] = f2b(S[qi][ig]*inv);
  }

  // phase B: O = P @ V via MFMA; K in two 256-halves, wave w = col-tile
  int w = tid >> 6, l = tid & 63;
  int arow = l & 15, kgrp = l >> 4;
  facc4 acc = {0.f, 0.f, 0.f, 0.f};
  for (int kh = 0; kh < 2; ++kh) {
    __syncthreads();   // kh=0: P writes done (+ kc reads long done); kh=1: prev MFMA reads done
    // stage V^T half: vTh[col][k-kh*256], paired k-rows packed into dwords
    for (int i = tid; i < 2048; i += 256) {
      int m2 = (i & 127) << 1;          // local k rows m2, m2+1
      int cc = (i >> 7) << 2;           // col base
      const bf16* gp = vvc + ((long)(lt*NN + kh*256 + m2))*128 + 64 + cc;
      ushort4 a = *(const ushort4*)(gp);
      ushort4 b = *(const ushort4*)(gp + 128);
      *(unsigned*)(vTh + (cc+0)*264 + m2) = (unsigned)a.x | ((unsigned)b.x << 16);
      *(unsigned*)(vTh + (cc+1)*264 + m2) = (unsigned)a.y | ((unsigned)b.y << 16);
      *(unsigned*)(vTh + (cc+2)*264 + m2) = (unsigned)a.z | ((unsigned)b.z << 16);
      *(unsigned*)(vTh + (cc+3)*264 + m2) = (unsigned)a.w | ((unsigned)b.w << 16);
    }
    __syncthreads();
    const bf16* pa = P + arow*520 + kh*256 + kgrp*8;
    const bf16* pb = vTh + (w*16 + arow)*264 + kgrp*8;
    #pragma unroll
    for (int ks = 0; ks < 8; ++ks) {
      bfrag8 av = *(const bfrag8*)(pa + ks*32);
      bfrag8 bv = *(const bfrag8*)(pb + ks*32);
      acc = __builtin_amdgcn_mfma_f32_16x16x32_bf16(av, bv, acc, 0, 0, 0);
    }
  }
  // epilogue: C/D map col=lane&15, row=(lane>>4)*4+r
  long rb = ((long)gt*NN + qt*16)*64 + w*16 + arow;
  #pragma unroll
  for (int r = 0; r < 4; ++r) {
    int row = kgrp*4 + r;
    resid[rb + (long)row*64] += acc[r];
  }
}

// ---------------- LN1 ----------------
__global__ __launch_bounds__(256) void k_ln1(
  const float* __restrict__ resid, const float* __restrict__ gw, const float* __restrict__ bw,
  float* __restrict__ ln1o)
{
  int lane = threadIdx.x & 63;
  long r = (long)blockIdx.x*4 + (threadIdx.x >> 6);
  long base = r*64 + lane;
  float v = resid[base];
  float m = wsum64(v)*(1.f/64.f);
  float d = v - m;
  float var = wsum64(d*d)*(1.f/64.f);
  ln1o[base] = d*rsqrtf(var + 1e-5f)*gw[lane] + bw[lane];
}

// ---------------- LN2 + leaky + PE -> src ----------------
__global__ __launch_bounds__(256) void k_ln2_src(
  const float* __restrict__ mlpo, const float* __restrict__ resid,
  const float* __restrict__ gw, const float* __restrict__ bw,
  float* __restrict__ src)
{
  int lane = threadIdx.x & 63;
  long r = (long)blockIdx.x*4 + (threadIdx.x >> 6);
  long base = r*64 + lane;
  float v = mlpo[base] + resid[base];
  float m = wsum64(v)*(1.f/64.f);
  float d = v - m;
  float var = wsum64(d*d)*(1.f/64.f);
  float y = d*rsqrtf(var + 1e-5f)*gw[lane] + bw[lane];
  y = lk(y);
  float tf = (float)(r / NN);
  float dv = __expf(-(float)(lane & ~1) * 0.14391156831212787f);
  float pe = (lane & 1) ? cosf(tf*dv) : sinf(tf*dv);
  src[base] = y + pe;
}

// ---------------- head ----------------
__global__ __launch_bounds__(64) void k_head(
  const bf16* __restrict__ mqkv, const float* __restrict__ rts,
  const float* __restrict__ mow, const float* __restrict__ mob,
  const float* __restrict__ xsw, const float* __restrict__ xtw, const float* __restrict__ xtb,
  const float* __restrict__ hw, const float* __restrict__ hb,
  const float* __restrict__ linw, const float* __restrict__ linb,
  float* __restrict__ out)
{
  int n = blockIdx.x, o = threadIdx.x;
  __shared__ float ps[TT];
  __shared__ float buf[64], buf2[64];
  float mq = b2f(mqkv[((long)(TT-1)*NN + n)*192 + o]);
  for (int s = 0; s < TT; ++s) {
    float v = mq * b2f(mqkv[((long)s*NN + n)*192 + 64 + o]);
    v = wsum64(v);
    if (o == 0) ps[s] = v * SCALEV;
  }
  __syncthreads();
  float x = (o < TT) ? ps[o] : -INFINITY;
  float mx = wmax64(x);
  float e = (o < TT) ? __expf(x - mx) : 0.f;
  float se = wsum64(e);
  if (o < TT) ps[o] = e / se;
  __syncthreads();
  float acc = 0.f;
  for (int s = 0; s < TT; ++s) acc += ps[s]*b2f(mqkv[((long)s*NN + n)*192 + 128 + o]);
  buf[o] = acc;
  __syncthreads();
  float acc2 = mob[o];
  for (int k = 0; k < 64; ++k) acc2 += buf[k]*mow[o*64 + k];
  float m2 = wsum64(acc2)*(1.f/64.f);
  float d2 = acc2 - m2;
  float var2 = wsum64(d2*d2)*(1.f/64.f);
  float a = d2*rsqrtf(var2 + 1e-5f);
  float rt = rts[(long)n*64 + o];
  __syncthreads();
  buf[o] = a; buf2[o] = rt;
  __syncthreads();
  float pre = xtb[o];
  for (int k = 0; k < 64; ++k) pre += buf[k]*xsw[o*64 + k] + buf2[k]*xtw[o*64 + k];
  float zg = sgm(pre);
  float u = zg*a + (1.f - zg)*rt;
  __syncthreads();
  buf[o] = u;
  __syncthreads();
  float f = hb[o];
  for (int k = 0; k < 64; ++k) f += buf[k]*hw[o*64 + k];
  f = lk(f);
  float tot = wsum64(f * linw[o]);
  if (o == 0) out[n] = tot + linb[0];
}

// =======================================================================
extern "C" void kernel_launch(void* const* d_in, const int* in_sizes, int n_in,
                              void* d_out, int out_size, void* d_ws, size_t ws_size,
                              hipStream_t stream)
{
  const float* x    = (const float*)d_in[0];
  const int*   ei   = (const int*)  d_in[1];
  const float* fcw  = (const float*)d_in[2];
  const float* fcb  = (const float*)d_in[3];
  const float* wih0 = (const float*)d_in[4];
  const float* whh0 = (const float*)d_in[5];
  const float* bih0 = (const float*)d_in[6];
  const float* bhh0 = (const float*)d_in[7];
  const float* wih1 = (const float*)d_in[8];
  const float* whh1 = (const float*)d_in[9];
  const float* bih1 = (const float*)d_in[10];
  const float* bhh1 = (const float*)d_in[11];
  const float* dmqw = (const float*)d_in[12];
  const float* dmkw = (const float*)d_in[13];
  const float* dmvw = (const float*)d_in[14];
  const float* dmvb = (const float*)d_in[15];
  const float* ssqw = (const float*)d_in[16];
  const float* sskw = (const float*)d_in[17];
  const float* ssvw = (const float*)d_in[18];
  const float* ssvb = (const float*)d_in[19];
  const float* ln1g = (const float*)d_in[20];
  const float* ln1b = (const float*)d_in[21];
  const float* ln2g = (const float*)d_in[22];
  const float* ln2b = (const float*)d_in[23];
  const float* mw1  = (const float*)d_in[24];
  const float* mb1  = (const float*)d_in[25];
  const float* mw2  = (const float*)d_in[26];
  const float* mb2  = (const float*)d_in[27];
  const float* mhw  = (const float*)d_in[28];
  const float* mhb  = (const float*)d_in[29];
  const float* mow  = (const float*)d_in[30];
  const float* mob  = (const float*)d_in[31];
  const float* gxsw = (const float*)d_in[32];
  const float* gxtw = (const float*)d_in[33];
  const float* gxtb = (const float*)d_in[34];
  const float* ghw  = (const float*)d_in[35];
  const float* ghb  = (const float*)d_in[36];
  const float* linw = (const float*)d_in[37];
  const float* linb = (const float*)d_in[38];

  // ---- workspace layout (~43.6 MB envelope, unchanged) ----
  char* base = (char*)d_ws;
  float*  xs    = (float*)(base);                 // xs f32; later mlpo f32
  char*   Rb    = base + 7864320;                 // shared region:
  float*  qkc   = (float*)Rb;                     //   per-chunk qs|ks f32 (2.62MB)
  bf16*   vvc   = (bf16*)(Rb + 2621440);          //   per-chunk v|vs bf16 (1.31MB)
  float*  qkx   = (float*)(Rb + 3932160);         //   per-chunk exact q|k f32 (2.62MB)
  float*  mlph  = (float*)Rb;                     //   later: mlp hidden f32
  bf16*   mqkv  = (bf16*)Rb;                      //   later: mha qkv bf16
  bf16*   g0    = (bf16*)(base + 23592960);
  float*  resid = (float*)(base + 27525120);
  float*  ln1o  = (float*)(base + 35389440);
  float*  rts   = (float*)(base + 43253760);
  unsigned int* msk = (unsigned int*)(base + 43384832);
  float*  Wc    = (float*)(base + 43417600);      // 4*4096 f32 (qs|ks|v|vs)
  float*  bcV   = (float*)(base + 43483136);      // 128 f32
  float*  Wqk   = (float*)(base + 43483648);      // 128*64 f32 (q|k)
  float*  mlpo  = xs;
  float*  src   = ln1o;
  float*  outb  = (float*)d_out;
  float*  attn  = outb + 512;
  // gi staged in d_out's attn region — dead before k_attn_dyn writes probs
  float*  gi    = (float*)((char*)d_out + 2048);

  k_zero_u32<<<dim3(32), 256, 0, stream>>>(msk, 512*16);
  k_scatter_bits<<<dim3(32), 256, 0, stream>>>(ei, msk);
  k_pack<<<dim3(97), 256, 0, stream>>>(ssqw, sskw, dmvw, ssvw, dmvb, ssvb, dmqw, dmkw, Wc, bcV, Wqk);
  k_fcin<<<dim3(TN*64/256), 256, 0, stream>>>(x, fcw, fcb, xs, resid);
  // GRU layer 0
  k_gemm<float,float><<<dim3(480, 3), 256, 0, stream>>>(xs, wih0, bih0, gi, 64, 192, 1);
  k_gru<<<dim3(NN), 192, 0, stream>>>(gi, whh0, bhh0, g0, nullptr, 0);
  // GRU layer 1
  k_gemm<bf16,float><<<dim3(480, 3), 256, 0, stream>>>(g0, wih1, bih1, gi, 64, 192, 1);
  k_gru<<<dim3(NN), 192, 0, stream>>>(gi, whh1, bhh1, nullptr, rts, 1);
  // attention in 6 t-chunks
  for (int tc = 0; tc < NCHK; ++tc) {
    const float* xsc = xs + (size_t)tc*TCH*NN*64;
    k_qkx<<<dim3(80, 2), 256, 0, stream>>>(xsc, Wqk, qkx);
    k_gemm<float,float><<<dim3(80, 2), 256, 0, stream>>>(xsc, Wc, nullptr, qkc, 64, 128, 0);
    k_gemm<float,bf16 ><<<dim3(80, 2), 256, 0, stream>>>(xsc, Wc + 2*4096, bcV, vvc, 64, 128, 0);
    k_attn_dyn<<<dim3(32, 2, TCH), 256, 0, stream>>>(qkx, vvc, attn, resid, tc);
    k_attn_st <<<dim3(32, 1, TCH), 256, 0, stream>>>(qkc, vvc, msk, resid, tc);
  }
  // LN1 -> MLP -> LN2+PE
  k_ln1<<<dim3(TN/4), 256, 0, stream>>>(resid, ln1g, ln1b, ln1o);
  k_gemm<float,float><<<dim3(480, 2), 256, 0, stream>>>(ln1o, mw1, mb1, mlph, 64, 128, 0);
  k_gemm<float,float><<<dim3(480, 1), 256, 0, stream>>>(mlph, mw2, mb2, mlpo, 128, 64, 0);
  k_ln2_src<<<dim3(TN/4), 256, 0, stream>>>(mlpo, resid, ln2g, ln2b, src);
  // mha in-projection + head
  k_gemm<float,bf16 ><<<dim3(480, 3), 256, 0, stream>>>(src, mhw, mhb, mqkv, 64, 192, 0);
  k_head<<<dim3(NN), 64, 0, stream>>>(mqkv, rts, mow, mob, gxsw, gxtw, gxtb, ghw, ghb, linw, linb, outb);
}

// Round 3
// 903.505 us; speedup vs baseline: 1.6008x; 1.2625x over previous
//
#include <hip/hip_runtime.h>
#include <hip/hip_bf16.h>

#define NN 512
#define TT 60
#define DFF 6
#define EE 8192
#define TN (TT*NN)
#define TCH 20          // t-chunk size
#define NCHK 3          // number of t-chunks
#define SCALEV 0.125f
#define NEGV -1.0e10f

typedef __hip_bfloat16 bf16;
using bfrag8 = __attribute__((ext_vector_type(8))) short;   // 8 bf16 (4 VGPRs)
using facc4  = __attribute__((ext_vector_type(4))) float;   // 4 f32 acc

__device__ __forceinline__ float b2f(bf16 v){ return __bfloat162float(v); }
__device__ __forceinline__ bf16 f2b(float v){ return __float2bfloat16(v); }
__device__ __forceinline__ float lk(float x){ return x >= 0.f ? x : 0.01f*x; }
__device__ __forceinline__ float sgm(float x){ return 1.f/(1.f+__expf(-x)); }

__device__ __forceinline__ float ldf(const float* p, long i){ return p[i]; }
__device__ __forceinline__ float ldf(const bf16* p, long i){ return b2f(p[i]); }
__device__ __forceinline__ void stf(float* p, long i, float v){ p[i] = v; }
__device__ __forceinline__ void stf(bf16* p, long i, float v){ p[i] = f2b(v); }

__device__ __forceinline__ float wsum64(float v){
  #pragma unroll
  for (int off = 32; off; off >>= 1) v += __shfl_xor(v, off, 64);
  return v;
}
__device__ __forceinline__ float wmax64(float v){
  #pragma unroll
  for (int off = 32; off; off >>= 1) v = fmaxf(v, __shfl_xor(v, off, 64));
  return v;
}

// ---------------- adjacency bitmask ----------------
__global__ __launch_bounds__(256) void k_zero_u32(unsigned int* __restrict__ p, int n){
  int i = blockIdx.x*256 + threadIdx.x;
  if (i < n) p[i] = 0u;
}
__global__ __launch_bounds__(256) void k_scatter_bits(const int* __restrict__ ei, unsigned int* __restrict__ msk){
  int e = blockIdx.x*256 + threadIdx.x;
  if (e < EE) {
    int u = ei[e], v = ei[EE + e];
    atomicOr(&msk[u*16 + (v >> 5)], 1u << (v & 31));
  }
}

// ---------------- pack: Wall f32 = q|k|qs|ks|v|vs (6x64x64) ; bcV = vb|vsb ----------------
__global__ __launch_bounds__(256) void k_pack(
  const float* __restrict__ qw, const float* __restrict__ kw,
  const float* __restrict__ qsw, const float* __restrict__ ksw,
  const float* __restrict__ vw, const float* __restrict__ vsw,
  const float* __restrict__ vb, const float* __restrict__ vsb,
  float* __restrict__ Wall, float* __restrict__ bcV)
{
  int idx = blockIdx.x*256 + threadIdx.x;
  if (idx < 6*4096) {
    int which = idx >> 12, rem = idx & 4095;
    const float* s = (which==0)?qw:(which==1)?kw:(which==2)?qsw:(which==3)?ksw:(which==4)?vw:vsw;
    Wall[idx] = s[rem];
  } else if (idx < 6*4096 + 128) {
    int o = idx - 6*4096;
    bcV[o] = (o < 64) ? vb[o] : vsb[o-64];
  }
}

// ---------------- fc_in: np-exact fp32 (seq-FMA over k, bias added after) ----------------
__global__ __launch_bounds__(256) void k_fcin(
  const float* __restrict__ x, const float* __restrict__ w, const float* __restrict__ b,
  float* __restrict__ xs, float* __restrict__ resid)
{
  long idx = (long)blockIdx.x*256 + threadIdx.x;   // < TN*64
  int o = idx & 63;
  long r = idx >> 6;                // r = t*NN + n
  int t = (int)(r / NN), n = (int)(r % NN);
  const float* xr = x + ((long)n*TT + t)*DFF;
  const float* wr = w + o*DFF;
  float acc = 0.f;
  #pragma unroll
  for (int j = 0; j < DFF; ++j) acc = fmaf(xr[j], wr[j], acc);
  float h = __fadd_rn(acc, b[o]);
  xs[idx] = h;
  resid[idx] = h;
}

// ---------------- fused per-chunk projection (np-exact seq-FMA over k=0..63) ----------------
// grid (rows/64, 6). bcn 0-1 -> qkx (q|k, f32), 2-3 -> qkc (qs|ks, f32),
// 4-5 -> vvc (v|vs, bf16, +bias). B = Wall + bcn*4096. One A-stage per block.
__global__ __launch_bounds__(256) void k_proj(
  const float* __restrict__ A, const float* __restrict__ Wall, const float* __restrict__ bcV,
  float* __restrict__ qkx, float* __restrict__ qkc, bf16* __restrict__ vvc)
{
  __shared__ float As[64][65];
  __shared__ float Bs[64][65];
  int rt = blockIdx.x, bcn = blockIdx.y;
  const float* B = Wall + bcn*4096;
  int tid = threadIdx.x;
  int tx = tid & 15, ty = tid >> 4;
  float acc[4][4] = {{0.f}};
  #pragma unroll
  for (int i = 0; i < 16; ++i) {
    int idx = i*256 + tid;
    int m = idx >> 6, kk = idx & 63;
    As[kk][m] = A[(long)(rt*64 + m)*64 + kk];
    Bs[kk][m] = B[(long)m*64 + kk];
  }
  __syncthreads();
  for (int kk = 0; kk < 64; ++kk) {
    float a0 = As[kk][ty*4+0], a1 = As[kk][ty*4+1], a2 = As[kk][ty*4+2], a3 = As[kk][ty*4+3];
    float b0 = Bs[kk][tx*4+0], b1 = Bs[kk][tx*4+1], b2v = Bs[kk][tx*4+2], b3 = Bs[kk][tx*4+3];
    acc[0][0] = fmaf(a0,b0,acc[0][0]); acc[0][1] = fmaf(a0,b1,acc[0][1]); acc[0][2] = fmaf(a0,b2v,acc[0][2]); acc[0][3] = fmaf(a0,b3,acc[0][3]);
    acc[1][0] = fmaf(a1,b0,acc[1][0]); acc[1][1] = fmaf(a1,b1,acc[1][1]); acc[1][2] = fmaf(a1,b2v,acc[1][2]); acc[1][3] = fmaf(a1,b3,acc[1][3]);
    acc[2][0] = fmaf(a2,b0,acc[2][0]); acc[2][1] = fmaf(a2,b1,acc[2][1]); acc[2][2] = fmaf(a2,b2v,acc[2][2]); acc[2][3] = fmaf(a2,b3,acc[2][3]);
    acc[3][0] = fmaf(a3,b0,acc[3][0]); acc[3][1] = fmaf(a3,b1,acc[3][1]); acc[3][2] = fmaf(a3,b2v,acc[3][2]); acc[3][3] = fmaf(a3,b3,acc[3][3]);
  }
  if (bcn < 4) {
    float* C = (bcn < 2) ? qkx : qkc;
    int cb = (bcn & 1)*64;
    #pragma unroll
    for (int i = 0; i < 4; ++i) {
      long ro = (long)(rt*64 + ty*4 + i)*128 + cb + tx*4;
      #pragma unroll
      for (int j = 0; j < 4; ++j) C[ro + j] = acc[i][j];
    }
  } else {
    int cb = (bcn - 4)*64;
    float bv[4];
    #pragma unroll
    for (int j = 0; j < 4; ++j) bv[j] = bcV[cb + tx*4 + j];
    #pragma unroll
    for (int i = 0; i < 4; ++i) {
      long ro = (long)(rt*64 + ty*4 + i)*128 + cb + tx*4;
      #pragma unroll
      for (int j = 0; j < 4; ++j) vvc[ro + j] = f2b(acc[i][j] + bv[j]);
    }
  }
}

// ---------------- generic projection GEMM (fp32, tolerant paths) ----------------
template<typename TA, typename TC>
__global__ __launch_bounds__(256) void k_gemm(
  const TA* __restrict__ A, const float* __restrict__ B, const float* __restrict__ bias,
  TC* __restrict__ C, int KD, int NC, int gather)
{
  __shared__ float As[64][65];
  __shared__ float Bs[64][65];
  int rt = blockIdx.x, bcn = blockIdx.y;
  int tid = threadIdx.x;
  int tx = tid & 15, ty = tid >> 4;
  float acc[4][4] = {{0.f}};
  int nch = KD >> 6;
  for (int kc = 0; kc < nch; ++kc) {
    __syncthreads();
    #pragma unroll
    for (int i = 0; i < 16; ++i) {
      int idx = i*256 + tid;
      int m = idx >> 6, kk = idx & 63;
      long aoff;
      int r = rt*64 + m;
      if (gather) { int n = r / TT, t = r - n*TT; aoff = ((long)t*NN + n)*64 + kk; }
      else aoff = (long)r*KD + kc*64 + kk;
      As[kk][m] = ldf(A, aoff);
      int col = bcn*64 + m;
      Bs[kk][m] = B[(long)col*KD + kc*64 + kk];
    }
    __syncthreads();
    #pragma unroll 8
    for (int kk = 0; kk < 64; ++kk) {
      float a0 = As[kk][ty*4+0], a1 = As[kk][ty*4+1], a2 = As[kk][ty*4+2], a3 = As[kk][ty*4+3];
      float b0 = Bs[kk][tx*4+0], b1 = Bs[kk][tx*4+1], b2v = Bs[kk][tx*4+2], b3 = Bs[kk][tx*4+3];
      acc[0][0] += a0*b0; acc[0][1] += a0*b1; acc[0][2] += a0*b2v; acc[0][3] += a0*b3;
      acc[1][0] += a1*b0; acc[1][1] += a1*b1; acc[1][2] += a1*b2v; acc[1][3] += a1*b3;
      acc[2][0] += a2*b0; acc[2][1] += a2*b1; acc[2][2] += a2*b2v; acc[2][3] += a2*b3;
      acc[3][0] += a3*b0; acc[3][1] += a3*b1; acc[3][2] += a3*b2v; acc[3][3] += a3*b3;
    }
  }
  float bv[4];
  #pragma unroll
  for (int j = 0; j < 4; ++j) bv[j] = bias ? bias[bcn*64 + tx*4 + j] : 0.f;
  #pragma unroll
  for (int i = 0; i < 4; ++i) {
    long ro = (long)(rt*64 + ty*4 + i)*NC + bcn*64 + tx*4;
    #pragma unroll
    for (int j = 0; j < 4; ++j) stf(C, ro + j, acc[i][j] + bv[j]);
  }
}

// ---------------- GRU recurrence: one block (192 thr) per batch row ----------------
// inner product via float4 LDS reads + 4 partial fp32 sums (tolerant path)
__global__ __launch_bounds__(192) void k_gru(
  const float* __restrict__ gi, const float* __restrict__ whh, const float* __restrict__ bhh,
  bf16* __restrict__ g_out, float* __restrict__ res_out, int layer)
{
  int n = blockIdx.x;
  int tid = threadIdx.x;
  int g = tid >> 6, o = tid & 63;
  __shared__ __align__(16) float h_lds[64];
  __shared__ float ghs[3][64];
  float4 w4[16];
  #pragma unroll
  for (int k4 = 0; k4 < 16; ++k4)
    w4[k4] = *(const float4*)&whh[(long)(g*64+o)*64 + k4*4];
  float bh = bhh[g*64+o];
  if (tid < 64) h_lds[tid] = 0.f;
  __syncthreads();
  const float4* h4 = (const float4*)h_lds;
  for (int t = 0; t < TT; ++t) {
    float p0 = 0.f, p1 = 0.f, p2 = 0.f, p3 = 0.f;
    #pragma unroll
    for (int k4 = 0; k4 < 16; ++k4) {
      float4 hv = h4[k4];
      p0 = fmaf(w4[k4].x, hv.x, p0);
      p1 = fmaf(w4[k4].y, hv.y, p1);
      p2 = fmaf(w4[k4].z, hv.z, p2);
      p3 = fmaf(w4[k4].w, hv.w, p3);
    }
    ghs[g][o] = bh + ((p0 + p1) + (p2 + p3));
    __syncthreads();
    if (tid < 64) {
      const float* gib = gi + ((long)n*TT + t)*192;
      float ir = gib[o], iz = gib[64+o], inn = gib[128+o];
      float r = sgm(ir + ghs[0][o]);
      float z = sgm(iz + ghs[1][o]);
      float nn2 = tanhf(inn + r*ghs[2][o]);
      float hn = (1.f - z)*nn2 + z*h_lds[o];
      h_lds[o] = hn;
      if (layer == 0) g_out[((long)t*NN + n)*64 + o] = f2b(hn);
      else if (t == TT-1) res_out[(long)n*64 + o] = lk(hn);
    }
    __syncthreads();
  }
}

// ---------------- dynamic attention v2 ----------------
// Phase A: np-exact scores (4-lane seq mul/add), float4 LDS traffic.
// Phase B: P@V via mfma_f32_16x16x32_bf16, V^T staged bf16.
// LDS 54400 B => 3 blocks/CU.
#define MULADD4(QV, KV) \
  v0 = __fadd_rn(v0, __fmul_rn((QV).x, (KV).x)); \
  v1 = __fadd_rn(v1, __fmul_rn((QV).y, (KV).y)); \
  v2 = __fadd_rn(v2, __fmul_rn((QV).z, (KV).z)); \
  v3 = __fadd_rn(v3, __fmul_rn((QV).w, (KV).w));

__global__ __launch_bounds__(256, 3) void k_attn_dyn(
  const float* __restrict__ qkx, const bf16* __restrict__ vvc,
  float* __restrict__ attn_out, float* __restrict__ resid, int tc)
{
  // region A [0,33280): sc f32[16][520] (phase A) | vT bf16[32][520] (phase B)
  // region B [33280,54016): kt f32[128][36] + qtl f32[16][36] (phase A)
  //                          | p_lds bf16[16][520] + red f32[2][272] (phase B)
  __shared__ __align__(16) char smem[54400];
  float* sc    = (float*)smem;                     // [16][520]
  bf16*  vT    = (bf16*)smem;                      // [32][520]
  float* kt    = (float*)(smem + 33280);           // [128][36]
  bf16*  p_lds = (bf16*)(smem + 33280);            // [16][520]
  float* red   = (float*)(smem + 49920);           // [2][16*17]
  float* qtl   = (float*)(smem + 51712);           // [16][36]
  float* means = (float*)(smem + 54016);           // [16]
  float* part  = (float*)(smem + 54080);           // [16][5]

  int qt = blockIdx.x, h = blockIdx.y, lt = blockIdx.z;
  int gt = tc*TCH + lt;
  int tid = threadIdx.x, tx = tid & 31, grp = tid >> 5;
  int qbase = grp*2;
  int qce = h*32, kce = 64 + h*32;

  // stage q tile [16][32] (float4)
  for (int i = tid; i < 128; i += 256) {
    int row = i >> 3, jj = (i & 7) << 2;
    *(float4*)(qtl + row*36 + jj) =
      *(const float4*)(qkx + ((long)(lt*NN + qt*16 + row))*128 + qce + jj);
  }

  float S[2][16];
  for (int p = 0; p < 4; ++p) {
    __syncthreads();
    for (int i = tid; i < 1024; i += 256) {
      int row = i >> 3, jj = (i & 7) << 2;
      *(float4*)(kt + row*36 + jj) =
        *(const float4*)(qkx + ((long)(lt*NN + p*128 + row))*128 + kce + jj);
    }
    __syncthreads();
    #pragma unroll
    for (int ii = 0; ii < 4; ++ii) {
      int m = tx + 32*ii;
      const float4* kr4 = (const float4*)(kt + m*36);
      float4 k0 = kr4[0], k1 = kr4[1], k2 = kr4[2], k3 = kr4[3];
      float4 k4 = kr4[4], k5 = kr4[5], k6 = kr4[6], k7 = kr4[7];
      #pragma unroll
      for (int qi = 0; qi < 2; ++qi) {
        const float4* qr4 = (const float4*)(qtl + (qbase+qi)*36);
        // numpy einsum baseline-SIMD emulation: 4 lanes, sequential unfused
        // mul+add per lane over d = l, l+4, ..., l+28; SSE3 hadd tree at end.
        float v0 = 0.f, v1 = 0.f, v2 = 0.f, v3 = 0.f;
        float4 qv;
        qv = qr4[0]; MULADD4(qv, k0);
        qv = qr4[1]; MULADD4(qv, k1);
        qv = qr4[2]; MULADD4(qv, k2);
        qv = qr4[3]; MULADD4(qv, k3);
        qv = qr4[4]; MULADD4(qv, k4);
        qv = qr4[5]; MULADD4(qv, k5);
        qv = qr4[6]; MULADD4(qv, k6);
        qv = qr4[7]; MULADD4(qv, k7);
        float s = __fadd_rn(__fadd_rn(v0, v1), __fadd_rn(v2, v3));
        s = s * 0.125f;   // exact pow2 scale
        S[qi][p*4+ii] = s;
        sc[(qbase+qi)*520 + p*128 + m] = s;
      }
    }
  }
  __syncthreads();
  // numpy pairwise mean over 512 (per row): 4x128-base-blocks then tree
  if (tid < 64) {
    int row = tid >> 2, b = tid & 3;
    const float* a = sc + row*520 + b*128;
    float r0 = a[0], r1 = a[1], r2 = a[2], r3 = a[3];
    float r4 = a[4], r5 = a[5], r6 = a[6], r7 = a[7];
    for (int i = 8; i < 128; i += 8) {
      r0 = __fadd_rn(r0, a[i+0]); r1 = __fadd_rn(r1, a[i+1]);
      r2 = __fadd_rn(r2, a[i+2]); r3 = __fadd_rn(r3, a[i+3]);
      r4 = __fadd_rn(r4, a[i+4]); r5 = __fadd_rn(r5, a[i+5]);
      r6 = __fadd_rn(r6, a[i+6]); r7 = __fadd_rn(r7, a[i+7]);
    }
    part[row*5 + b] = __fadd_rn(
        __fadd_rn(__fadd_rn(r0, r1), __fadd_rn(r2, r3)),
        __fadd_rn(__fadd_rn(r4, r5), __fadd_rn(r6, r7)));
  }
  __syncthreads();
  if (tid < 16) {
    float s = __fadd_rn(__fadd_rn(part[tid*5+0], part[tid*5+1]),
                        __fadd_rn(part[tid*5+2], part[tid*5+3]));
    means[tid] = s * (1.f/512.f);   // exact pow2 divide
  }
  __syncthreads();

  long obase = ((long)(gt*2 + h))*NN*NN;
  #pragma unroll
  for (int qi = 0; qi < 2; ++qi) {
    float mn = means[qbase + qi];
    unsigned kmask = 0; float lm = -INFINITY;
    #pragma unroll
    for (int ig = 0; ig < 16; ++ig) {
      if (S[qi][ig] >= mn) { kmask |= (1u << ig); lm = fmaxf(lm, S[qi][ig]); }
    }
    #pragma unroll
    for (int mk = 1; mk < 32; mk <<= 1) lm = fmaxf(lm, __shfl_xor(lm, mk, 64));
    float e[16]; float se = 0.f;
    #pragma unroll
    for (int ig = 0; ig < 16; ++ig) {
      e[ig] = ((kmask >> ig) & 1u) ? __expf(S[qi][ig] - lm) : 0.f;
      se += e[ig];
    }
    #pragma unroll
    for (int mk = 1; mk < 32; mk <<= 1) se += __shfl_xor(se, mk, 64);
    float inv = 1.f/se;
    float* rowp = attn_out + obase + (long)(qt*16 + qbase + qi)*NN;
    bf16* prow = p_lds + (qbase + qi)*520;
    #pragma unroll
    for (int ig = 0; ig < 16; ++ig) {
      float pr = e[ig]*inv;
      rowp[tx + 32*ig] = pr;
      prow[tx + 32*ig] = f2b(pr);
    }
  }

  // stage V transposed: vT[col][k], paired rows packed into dword writes
  for (int i = tid; i < 2048; i += 256) {
    int m2 = (i & 255) << 1;          // k rows m2, m2+1
    int cc = (i >> 8) << 2;           // col base
    const bf16* gp = vvc + ((long)(lt*NN + m2))*128 + qce + cc;
    ushort4 a = *(const ushort4*)(gp);
    ushort4 b = *(const ushort4*)(gp + 128);
    *(unsigned*)(vT + (cc+0)*520 + m2) = (unsigned)a.x | ((unsigned)b.x << 16);
    *(unsigned*)(vT + (cc+1)*520 + m2) = (unsigned)a.y | ((unsigned)b.y << 16);
    *(unsigned*)(vT + (cc+2)*520 + m2) = (unsigned)a.z | ((unsigned)b.z << 16);
    *(unsigned*)(vT + (cc+3)*520 + m2) = (unsigned)a.w | ((unsigned)b.w << 16);
  }
  __syncthreads();

  // phase B: O = P @ V via MFMA. wave w: col-tile nh=w&1, K-half kh=w>>1
  {
    int w = tid >> 6, l = tid & 63;
    int nh = w & 1, kh = w >> 1;
    int arow = l & 15, kgrp = l >> 4;
    facc4 acc = {0.f, 0.f, 0.f, 0.f};
    const bf16* pa = p_lds + arow*520 + kh*256 + kgrp*8;
    const bf16* pb = vT + (nh*16 + arow)*520 + kh*256 + kgrp*8;
    #pragma unroll
    for (int ks = 0; ks < 8; ++ks) {
      bfrag8 av = *(const bfrag8*)(pa + ks*32);
      bfrag8 bv = *(const bfrag8*)(pb + ks*32);
      acc = __builtin_amdgcn_mfma_f32_16x16x32_bf16(av, bv, acc, 0, 0, 0);
    }
    if (w >= 2) {
      #pragma unroll
      for (int r = 0; r < 4; ++r)
        red[nh*272 + (kgrp*4 + r)*17 + arow] = acc[r];
    }
    __syncthreads();
    if (w < 2) {
      long rb = ((long)gt*NN + qt*16)*64 + h*32 + nh*16 + arow;
      #pragma unroll
      for (int r = 0; r < 4; ++r) {
        int row = kgrp*4 + r;
        resid[rb + (long)row*64] += acc[r] + red[nh*272 + row*17 + arow];
      }
    }
  }
}

// ---------------- static attention v2 (fp32 scores, adjacency bitmask) ----------------
__global__ __launch_bounds__(256, 3) void k_attn_st(
  const float* __restrict__ qkc, const bf16* __restrict__ vvc,
  const unsigned int* __restrict__ msk, float* __restrict__ resid, int tc)
{
  // R0 [0,34816): kc f32[128][68] swizzled (phase A) | vTh bf16[64][264] (phase B)
  // R1 [34816,51456): q f32[16][68] (phase A) | P bf16[16][520] (phase B)
  __shared__ __align__(16) char smem[51456];
  float* kc  = (float*)smem;                 // [128][68] f32 (swizzled float4 units)
  bf16*  vTh = (bf16*)smem;                  // [64][264] bf16 (K-half of V^T)
  float* qtl = (float*)(smem + 34816);       // [16][68] f32
  bf16*  P   = (bf16*)(smem + 34816);        // [16][520] bf16 (overlays qtl after use)

  int qt = blockIdx.x, lt = blockIdx.z;
  int gt = tc*TCH + lt;
  int tid = threadIdx.x;
  int tx = tid & 31, grp = tid >> 5;
  int qbase = grp*2;

  float4* q4 = (float4*)qtl;    // stride 17 float4
  float4* k4 = (float4*)kc;     // stride 17 float4

  // stage q tile [16][64] f32 (1 float4 per thread, coalesced)
  {
    int m = tid >> 4, jc = tid & 15;
    q4[m*17 + jc] = *(const float4*)(qkc + ((long)(lt*NN + qt*16 + m))*128 + jc*4);
  }

  float S[2][16];
  for (int p = 0; p < 4; ++p) {
    __syncthreads();
    // stage kc chunk [128][64] f32, XOR-swizzled float4 units
    for (int i = tid; i < 2048; i += 256) {
      int m = i >> 4, jc = i & 15;
      k4[m*17 + (jc ^ ((m >> 2) & 3))] =
        *(const float4*)(qkc + ((long)(lt*NN + p*128 + m))*128 + 64 + jc*4);
    }
    __syncthreads();
    float acc00 = 0.f, acc01 = 0.f, acc02 = 0.f, acc03 = 0.f;
    float acc10 = 0.f, acc11 = 0.f, acc12 = 0.f, acc13 = 0.f;
    #pragma unroll 4
    for (int jc = 0; jc < 16; ++jc) {
      float4 q0 = q4[(qbase+0)*17 + jc];
      float4 q1 = q4[(qbase+1)*17 + jc];
      float4 kv;
      int m0 = tx;
      kv = k4[m0*17 + (jc ^ ((m0 >> 2) & 3))];
      acc00 += q0.x*kv.x + q0.y*kv.y + q0.z*kv.z + q0.w*kv.w;
      acc10 += q1.x*kv.x + q1.y*kv.y + q1.z*kv.z + q1.w*kv.w;
      int m1 = tx + 32;
      kv = k4[m1*17 + (jc ^ ((m1 >> 2) & 3))];
      acc01 += q0.x*kv.x + q0.y*kv.y + q0.z*kv.z + q0.w*kv.w;
      acc11 += q1.x*kv.x + q1.y*kv.y + q1.z*kv.z + q1.w*kv.w;
      int m2 = tx + 64;
      kv = k4[m2*17 + (jc ^ ((m2 >> 2) & 3))];
      acc02 += q0.x*kv.x + q0.y*kv.y + q0.z*kv.z + q0.w*kv.w;
      acc12 += q1.x*kv.x + q1.y*kv.y + q1.z*kv.z + q1.w*kv.w;
      int m3 = tx + 96;
      kv = k4[m3*17 + (jc ^ ((m3 >> 2) & 3))];
      acc03 += q0.x*kv.x + q0.y*kv.y + q0.z*kv.z + q0.w*kv.w;
      acc13 += q1.x*kv.x + q1.y*kv.y + q1.z*kv.z + q1.w*kv.w;
    }
    S[0][p*4+0] = acc00; S[0][p*4+1] = acc01; S[0][p*4+2] = acc02; S[0][p*4+3] = acc03;
    S[1][p*4+0] = acc10; S[1][p*4+1] = acc11; S[1][p*4+2] = acc12; S[1][p*4+3] = acc13;
  }
  __syncthreads();   // kc + qtl dead after this point

  // scale + mask + softmax (fp32, register-resident)
  #pragma unroll
  for (int qi = 0; qi < 2; ++qi) {
    #pragma unroll
    for (int ig = 0; ig < 16; ++ig) S[qi][ig] *= SCALEV;
    float lm = -INFINITY;
    #pragma unroll
    for (int ig = 0; ig < 16; ++ig) {
      bool keep = ((msk[(qt*16 + qbase + qi)*16 + ig] >> tx) & 1u) != 0u;
      float v = keep ? S[qi][ig] : NEGV;
      S[qi][ig] = v;
      lm = fmaxf(lm, v);
    }
    #pragma unroll
    for (int mk = 1; mk < 32; mk <<= 1) lm = fmaxf(lm, __shfl_xor(lm, mk, 64));
    float se = 0.f;
    #pragma unroll
    for (int ig = 0; ig < 16; ++ig) {
      float ev = __expf(S[qi][ig] - lm);
      S[qi][ig] = ev;
      se += ev;
    }
    #pragma unroll
    for (int mk = 1; mk < 32; mk <<= 1) se += __shfl_xor(se, mk, 64);
    float inv = 1.f / se;
    bf16* prow = P + (qbase + qi)*520;
    #pragma unroll
    for (int ig = 0; ig < 16; ++ig)
      prow[tx + 32*ig] = f2b(S[qi][ig]*inv);
  }

  // phase B: O = P @ V via MFMA; K in two 256-halves, wave w = col-tile
  int w = tid >> 6, l = tid & 63;
  int arow = l & 15, kgrp = l >> 4;
  facc4 acc = {0.f, 0.f, 0.f, 0.f};
  for (int kh = 0; kh < 2; ++kh) {
    __syncthreads();
    // stage V^T half: vTh[col][k-kh*256], paired k-rows packed into dwords
    for (int i = tid; i < 2048; i += 256) {
      int m2 = (i & 127) << 1;          // local k rows m2, m2+1
      int cc = (i >> 7) << 2;           // col base
      const bf16* gp = vvc + ((long)(lt*NN + kh*256 + m2))*128 + 64 + cc;
      ushort4 a = *(const ushort4*)(gp);
      ushort4 b = *(const ushort4*)(gp + 128);
      *(unsigned*)(vTh + (cc+0)*264 + m2) = (unsigned)a.x | ((unsigned)b.x << 16);
      *(unsigned*)(vTh + (cc+1)*264 + m2) = (unsigned)a.y | ((unsigned)b.y << 16);
      *(unsigned*)(vTh + (cc+2)*264 + m2) = (unsigned)a.z | ((unsigned)b.z << 16);
      *(unsigned*)(vTh + (cc+3)*264 + m2) = (unsigned)a.w | ((unsigned)b.w << 16);
    }
    __syncthreads();
    const bf16* pa = P + arow*520 + kh*256 + kgrp*8;
    const bf16* pb = vTh + (w*16 + arow)*264 + kgrp*8;
    #pragma unroll
    for (int ks = 0; ks < 8; ++ks) {
      bfrag8 av = *(const bfrag8*)(pa + ks*32);
      bfrag8 bv = *(const bfrag8*)(pb + ks*32);
      acc = __builtin_amdgcn_mfma_f32_16x16x32_bf16(av, bv, acc, 0, 0, 0);
    }
  }
  // epilogue: C/D map col=lane&15, row=(lane>>4)*4+r
  long rb = ((long)gt*NN + qt*16)*64 + w*16 + arow;
  #pragma unroll
  for (int r = 0; r < 4; ++r) {
    int row = kgrp*4 + r;
    resid[rb + (long)row*64] += acc[r];
  }
}

// ---------------- LN1 ----------------
__global__ __launch_bounds__(256) void k_ln1(
  const float* __restrict__ resid, const float* __restrict__ gw, const float* __restrict__ bw,
  float* __restrict__ ln1o)
{
  int lane = threadIdx.x & 63;
  long r = (long)blockIdx.x*4 + (threadIdx.x >> 6);
  long base = r*64 + lane;
  float v = resid[base];
  float m = wsum64(v)*(1.f/64.f);
  float d = v - m;
  float var = wsum64(d*d)*(1.f/64.f);
  ln1o[base] = d*rsqrtf(var + 1e-5f)*gw[lane] + bw[lane];
}

// ---------------- LN2 + leaky + PE -> src ----------------
__global__ __launch_bounds__(256) void k_ln2_src(
  const float* __restrict__ mlpo, const float* __restrict__ resid,
  const float* __restrict__ gw, const float* __restrict__ bw,
  float* __restrict__ src)
{
  int lane = threadIdx.x & 63;
  long r = (long)blockIdx.x*4 + (threadIdx.x >> 6);
  long base = r*64 + lane;
  float v = mlpo[base] + resid[base];
  float m = wsum64(v)*(1.f/64.f);
  float d = v - m;
  float var = wsum64(d*d)*(1.f/64.f);
  float y = d*rsqrtf(var + 1e-5f)*gw[lane] + bw[lane];
  y = lk(y);
  float tf = (float)(r / NN);
  float dv = __expf(-(float)(lane & ~1) * 0.14391156831212787f);
  float pe = (lane & 1) ? cosf(tf*dv) : sinf(tf*dv);
  src[base] = y + pe;
}

// ---------------- head ----------------
__global__ __launch_bounds__(64) void k_head(
  const bf16* __restrict__ mqkv, const float* __restrict__ rts,
  const float* __restrict__ mow, const float* __restrict__ mob,
  const float* __restrict__ xsw, const float* __restrict__ xtw, const float* __restrict__ xtb,
  const float* __restrict__ hw, const float* __restrict__ hb,
  const float* __restrict__ linw, const float* __restrict__ linb,
  float* __restrict__ out)
{
  int n = blockIdx.x, o = threadIdx.x;
  __shared__ float ps[TT];
  __shared__ float buf[64], buf2[64];
  float mq = b2f(mqkv[((long)(TT-1)*NN + n)*192 + o]);
  for (int s = 0; s < TT; ++s) {
    float v = mq * b2f(mqkv[((long)s*NN + n)*192 + 64 + o]);
    v = wsum64(v);
    if (o == 0) ps[s] = v * SCALEV;
  }
  __syncthreads();
  float x = (o < TT) ? ps[o] : -INFINITY;
  float mx = wmax64(x);
  float e = (o < TT) ? __expf(x - mx) : 0.f;
  float se = wsum64(e);
  if (o < TT) ps[o] = e / se;
  __syncthreads();
  float acc = 0.f;
  for (int s = 0; s < TT; ++s) acc += ps[s]*b2f(mqkv[((long)s*NN + n)*192 + 128 + o]);
  buf[o] = acc;
  __syncthreads();
  float acc2 = mob[o];
  for (int k = 0; k < 64; ++k) acc2 += buf[k]*mow[o*64 + k];
  float m2 = wsum64(acc2)*(1.f/64.f);
  float d2 = acc2 - m2;
  float var2 = wsum64(d2*d2)*(1.f/64.f);
  float a = d2*rsqrtf(var2 + 1e-5f);
  float rt = rts[(long)n*64 + o];
  __syncthreads();
  buf[o] = a; buf2[o] = rt;
  __syncthreads();
  float pre = xtb[o];
  for (int k = 0; k < 64; ++k) pre += buf[k]*xsw[o*64 + k] + buf2[k]*xtw[o*64 + k];
  float zg = sgm(pre);
  float u = zg*a + (1.f - zg)*rt;
  __syncthreads();
  buf[o] = u;
  __syncthreads();
  float f = hb[o];
  for (int k = 0; k < 64; ++k) f += buf[k]*hw[o*64 + k];
  f = lk(f);
  float tot = wsum64(f * linw[o]);
  if (o == 0) out[n] = tot + linb[0];
}

// =======================================================================
extern "C" void kernel_launch(void* const* d_in, const int* in_sizes, int n_in,
                              void* d_out, int out_size, void* d_ws, size_t ws_size,
                              hipStream_t stream)
{
  const float* x    = (const float*)d_in[0];
  const int*   ei   = (const int*)  d_in[1];
  const float* fcw  = (const float*)d_in[2];
  const float* fcb  = (const float*)d_in[3];
  const float* wih0 = (const float*)d_in[4];
  const float* whh0 = (const float*)d_in[5];
  const float* bih0 = (const float*)d_in[6];
  const float* bhh0 = (const float*)d_in[7];
  const float* wih1 = (const float*)d_in[8];
  const float* whh1 = (const float*)d_in[9];
  const float* bih1 = (const float*)d_in[10];
  const float* bhh1 = (const float*)d_in[11];
  const float* dmqw = (const float*)d_in[12];
  const float* dmkw = (const float*)d_in[13];
  const float* dmvw = (const float*)d_in[14];
  const float* dmvb = (const float*)d_in[15];
  const float* ssqw = (const float*)d_in[16];
  const float* sskw = (const float*)d_in[17];
  const float* ssvw = (const float*)d_in[18];
  const float* ssvb = (const float*)d_in[19];
  const float* ln1g = (const float*)d_in[20];
  const float* ln1b = (const float*)d_in[21];
  const float* ln2g = (const float*)d_in[22];
  const float* ln2b = (const float*)d_in[23];
  const float* mw1  = (const float*)d_in[24];
  const float* mb1  = (const float*)d_in[25];
  const float* mw2  = (const float*)d_in[26];
  const float* mb2  = (const float*)d_in[27];
  const float* mhw  = (const float*)d_in[28];
  const float* mhb  = (const float*)d_in[29];
  const float* mow  = (const float*)d_in[30];
  const float* mob  = (const float*)d_in[31];
  const float* gxsw = (const float*)d_in[32];
  const float* gxtw = (const float*)d_in[33];
  const float* gxtb = (const float*)d_in[34];
  const float* ghw  = (const float*)d_in[35];
  const float* ghb  = (const float*)d_in[36];
  const float* linw = (const float*)d_in[37];
  const float* linb = (const float*)d_in[38];

  // ---- workspace layout (~43.6 MB envelope, unchanged) ----
  char* base = (char*)d_ws;
  float*  xs    = (float*)(base);                 // xs f32; later mlpo f32
  char*   Rb    = base + 7864320;                 // shared region (15.73 MB):
  float*  qkc   = (float*)Rb;                     //   per-chunk qs|ks f32 (5.24MB, TCH=20)
  bf16*   vvc   = (bf16*)(Rb + 5242880);          //   per-chunk v|vs bf16 (2.62MB)
  float*  qkx   = (float*)(Rb + 7864320);         //   per-chunk exact q|k f32 (5.24MB)
  float*  mlph  = (float*)Rb;                     //   later: mlp hidden f32 (15.73MB)
  bf16*   mqkv  = (bf16*)Rb;                      //   later: mha qkv bf16 (11.8MB)
  bf16*   g0    = (bf16*)(base + 23592960);
  float*  resid = (float*)(base + 27525120);
  float*  ln1o  = (float*)(base + 35389440);
  float*  rts   = (float*)(base + 43253760);
  unsigned int* msk = (unsigned int*)(base + 43384832);
  float*  Wall  = (float*)(base + 43417600);      // 6*4096 f32 (q|k|qs|ks|v|vs)
  float*  bcV   = (float*)(base + 43515904);      // 128 f32
  float*  mlpo  = xs;
  float*  src   = ln1o;
  float*  outb  = (float*)d_out;
  float*  attn  = outb + 512;
  // gi staged in d_out's attn region — dead before k_attn_dyn writes probs
  float*  gi    = (float*)((char*)d_out + 2048);

  k_zero_u32<<<dim3(32), 256, 0, stream>>>(msk, 512*16);
  k_scatter_bits<<<dim3(32), 256, 0, stream>>>(ei, msk);
  k_pack<<<dim3(97), 256, 0, stream>>>(dmqw, dmkw, ssqw, sskw, dmvw, ssvw, dmvb, ssvb, Wall, bcV);
  k_fcin<<<dim3(TN*64/256), 256, 0, stream>>>(x, fcw, fcb, xs, resid);
  // GRU layer 0
  k_gemm<float,float><<<dim3(480, 3), 256, 0, stream>>>(xs, wih0, bih0, gi, 64, 192, 1);
  k_gru<<<dim3(NN), 192, 0, stream>>>(gi, whh0, bhh0, g0, nullptr, 0);
  // GRU layer 1
  k_gemm<bf16,float><<<dim3(480, 3), 256, 0, stream>>>(g0, wih1, bih1, gi, 64, 192, 1);
  k_gru<<<dim3(NN), 192, 0, stream>>>(gi, whh1, bhh1, nullptr, rts, 1);
  // attention in 3 t-chunks of 20
  for (int tc = 0; tc < NCHK; ++tc) {
    const float* xsc = xs + (size_t)tc*TCH*NN*64;
    k_proj<<<dim3(TCH*NN/64, 6), 256, 0, stream>>>(xsc, Wall, bcV, qkx, qkc, vvc);
    k_attn_dyn<<<dim3(32, 2, TCH), 256, 0, stream>>>(qkx, vvc, attn, resid, tc);
    k_attn_st <<<dim3(32, 1, TCH), 256, 0, stream>>>(qkc, vvc, msk, resid, tc);
  }
  // LN1 -> MLP -> LN2+PE
  k_ln1<<<dim3(TN/4), 256, 0, stream>>>(resid, ln1g, ln1b, ln1o);
  k_gemm<float,float><<<dim3(480, 2), 256, 0, stream>>>(ln1o, mw1, mb1, mlph, 64, 128, 0);
  k_gemm<float,float><<<dim3(480, 1), 256, 0, stream>>>(mlph, mw2, mb2, mlpo, 128, 64, 0);
  k_ln2_src<<<dim3(TN/4), 256, 0, stream>>>(mlpo, resid, ln2g, ln2b, src);
  // mha in-projection + head
  k_gemm<float,bf16 ><<<dim3(480, 3), 256, 0, stream>>>(src, mhw, mhb, mqkv, 64, 192, 0);
  k_head<<<dim3(NN), 64, 0, stream>>>(mqkv, rts, mow, mob, gxsw, gxtw, gxtb, ghw, ghb, linw, linb, outb);
}

// Round 4
// 734.328 us; speedup vs baseline: 1.9696x; 1.2304x over previous
//
#include <hip/hip_runtime.h>
#include <hip/hip_bf16.h>

#define NN 512
#define TT 60
#define DFF 6
#define EE 8192
#define TN (TT*NN)
#define TCH 20          // t-chunk size
#define NCHK 3          // number of t-chunks
#define SCALEV 0.125f
#define NEGV -1.0e10f

typedef __hip_bfloat16 bf16;
using bfrag8 = __attribute__((ext_vector_type(8))) short;   // 8 bf16 (4 VGPRs)
using facc4  = __attribute__((ext_vector_type(4))) float;   // 4 f32 acc

__device__ __forceinline__ float b2f(bf16 v){ return __bfloat162float(v); }
__device__ __forceinline__ bf16 f2b(float v){ return __float2bfloat16(v); }
__device__ __forceinline__ float lk(float x){ return x >= 0.f ? x : 0.01f*x; }
__device__ __forceinline__ float sgm(float x){ return 1.f/(1.f+__expf(-x)); }

__device__ __forceinline__ float ldf(const float* p, long i){ return p[i]; }
__device__ __forceinline__ float ldf(const bf16* p, long i){ return b2f(p[i]); }
__device__ __forceinline__ void stf(float* p, long i, float v){ p[i] = v; }
__device__ __forceinline__ void stf(bf16* p, long i, float v){ p[i] = f2b(v); }

__device__ __forceinline__ float4 ld4f(const float* p){ return *(const float4*)p; }
__device__ __forceinline__ float4 ld4f(const bf16* p){
  ushort4 u = *(const ushort4*)p;
  float4 f;
  f.x = b2f(*(const bf16*)&u.x);
  f.y = b2f(*(const bf16*)&u.y);
  f.z = b2f(*(const bf16*)&u.z);
  f.w = b2f(*(const bf16*)&u.w);
  return f;
}

__device__ __forceinline__ float wsum64(float v){
  #pragma unroll
  for (int off = 32; off; off >>= 1) v += __shfl_xor(v, off, 64);
  return v;
}
__device__ __forceinline__ float wmax64(float v){
  #pragma unroll
  for (int off = 32; off; off >>= 1) v = fmaxf(v, __shfl_xor(v, off, 64));
  return v;
}

// ---------------- adjacency bitmask ----------------
__global__ __launch_bounds__(256) void k_zero_u32(unsigned int* __restrict__ p, int n){
  int i = blockIdx.x*256 + threadIdx.x;
  if (i < n) p[i] = 0u;
}
__global__ __launch_bounds__(256) void k_scatter_bits(const int* __restrict__ ei, unsigned int* __restrict__ msk){
  int e = blockIdx.x*256 + threadIdx.x;
  if (e < EE) {
    int u = ei[e], v = ei[EE + e];
    atomicOr(&msk[u*16 + (v >> 5)], 1u << (v & 31));
  }
}

// ---------------- pack: Wall f32 = q|k|qs|ks|v|vs (6x64x64) ; bcV = vb|vsb ----------------
__global__ __launch_bounds__(256) void k_pack(
  const float* __restrict__ qw, const float* __restrict__ kw,
  const float* __restrict__ qsw, const float* __restrict__ ksw,
  const float* __restrict__ vw, const float* __restrict__ vsw,
  const float* __restrict__ vb, const float* __restrict__ vsb,
  float* __restrict__ Wall, float* __restrict__ bcV)
{
  int idx = blockIdx.x*256 + threadIdx.x;
  if (idx < 6*4096) {
    int which = idx >> 12, rem = idx & 4095;
    const float* s = (which==0)?qw:(which==1)?kw:(which==2)?qsw:(which==3)?ksw:(which==4)?vw:vsw;
    Wall[idx] = s[rem];
  } else if (idx < 6*4096 + 128) {
    int o = idx - 6*4096;
    bcV[o] = (o < 64) ? vb[o] : vsb[o-64];
  }
}

// ---------------- fc_in: np-exact fp32 (seq-FMA over k, bias added after) ----------------
__global__ __launch_bounds__(256) void k_fcin(
  const float* __restrict__ x, const float* __restrict__ w, const float* __restrict__ b,
  float* __restrict__ xs, float* __restrict__ resid)
{
  long idx = (long)blockIdx.x*256 + threadIdx.x;   // < TN*64
  int o = idx & 63;
  long r = idx >> 6;                // r = t*NN + n
  int t = (int)(r / NN), n = (int)(r % NN);
  const float* xr = x + ((long)n*TT + t)*DFF;
  const float* wr = w + o*DFF;
  float acc = 0.f;
  #pragma unroll
  for (int j = 0; j < DFF; ++j) acc = fmaf(xr[j], wr[j], acc);
  float h = __fadd_rn(acc, b[o]);
  xs[idx] = h;
  resid[idx] = h;
}

// ---------------- fused per-chunk projection (np-exact seq-FMA over k=0..63) ----------------
// grid (rows/64, 6). bcn 0-1 -> qkx (q|k, f32), 2-3 -> qkc (qs|ks, f32),
// 4-5 -> vvc (v|vs, bf16, +bias). B = Wall + bcn*4096.
// LDS stride 68: float4 staging (coalesced global, 4x-conflict writes accepted),
// float4 inner reads (a = 16-lane broadcast, b <= 2-way).
__global__ __launch_bounds__(256) void k_proj(
  const float* __restrict__ A, const float* __restrict__ Wall, const float* __restrict__ bcV,
  float* __restrict__ qkx, float* __restrict__ qkc, bf16* __restrict__ vvc)
{
  __shared__ float As[64][68];
  __shared__ float Bs[64][68];
  int rt = blockIdx.x, bcn = blockIdx.y;
  const float* B = Wall + bcn*4096;
  int tid = threadIdx.x;
  int tx = tid & 15, ty = tid >> 4;
  float acc[4][4] = {{0.f}};
  #pragma unroll
  for (int i = 0; i < 4; ++i) {
    int t = i*256 + tid;
    int m = t >> 4, kq = (t & 15)*4;
    float4 av = *(const float4*)&A[(long)(rt*64 + m)*64 + kq];
    As[kq+0][m] = av.x; As[kq+1][m] = av.y; As[kq+2][m] = av.z; As[kq+3][m] = av.w;
    float4 bv = *(const float4*)&B[(long)m*64 + kq];
    Bs[kq+0][m] = bv.x; Bs[kq+1][m] = bv.y; Bs[kq+2][m] = bv.z; Bs[kq+3][m] = bv.w;
  }
  __syncthreads();
  for (int kk = 0; kk < 64; ++kk) {
    float4 a4 = *(const float4*)&As[kk][ty*4];
    float4 b4 = *(const float4*)&Bs[kk][tx*4];
    acc[0][0] = fmaf(a4.x,b4.x,acc[0][0]); acc[0][1] = fmaf(a4.x,b4.y,acc[0][1]); acc[0][2] = fmaf(a4.x,b4.z,acc[0][2]); acc[0][3] = fmaf(a4.x,b4.w,acc[0][3]);
    acc[1][0] = fmaf(a4.y,b4.x,acc[1][0]); acc[1][1] = fmaf(a4.y,b4.y,acc[1][1]); acc[1][2] = fmaf(a4.y,b4.z,acc[1][2]); acc[1][3] = fmaf(a4.y,b4.w,acc[1][3]);
    acc[2][0] = fmaf(a4.z,b4.x,acc[2][0]); acc[2][1] = fmaf(a4.z,b4.y,acc[2][1]); acc[2][2] = fmaf(a4.z,b4.z,acc[2][2]); acc[2][3] = fmaf(a4.z,b4.w,acc[2][3]);
    acc[3][0] = fmaf(a4.w,b4.x,acc[3][0]); acc[3][1] = fmaf(a4.w,b4.y,acc[3][1]); acc[3][2] = fmaf(a4.w,b4.z,acc[3][2]); acc[3][3] = fmaf(a4.w,b4.w,acc[3][3]);
  }
  if (bcn < 4) {
    float* C = (bcn < 2) ? qkx : qkc;
    int cb = (bcn & 1)*64;
    #pragma unroll
    for (int i = 0; i < 4; ++i) {
      long ro = (long)(rt*64 + ty*4 + i)*128 + cb + tx*4;
      #pragma unroll
      for (int j = 0; j < 4; ++j) C[ro + j] = acc[i][j];
    }
  } else {
    int cb = (bcn - 4)*64;
    float bv[4];
    #pragma unroll
    for (int j = 0; j < 4; ++j) bv[j] = bcV[cb + tx*4 + j];
    #pragma unroll
    for (int i = 0; i < 4; ++i) {
      long ro = (long)(rt*64 + ty*4 + i)*128 + cb + tx*4;
      #pragma unroll
      for (int j = 0; j < 4; ++j) vvc[ro + j] = f2b(acc[i][j] + bv[j]);
    }
  }
}

// ---------------- generic projection GEMM (fp32, tolerant paths) ----------------
template<typename TA, typename TC>
__global__ __launch_bounds__(256) void k_gemm(
  const TA* __restrict__ A, const float* __restrict__ B, const float* __restrict__ bias,
  TC* __restrict__ C, int KD, int NC, int gather)
{
  __shared__ float As[64][68];
  __shared__ float Bs[64][68];
  int rt = blockIdx.x, bcn = blockIdx.y;
  int tid = threadIdx.x;
  int tx = tid & 15, ty = tid >> 4;
  float acc[4][4] = {{0.f}};
  int nch = KD >> 6;
  for (int kc = 0; kc < nch; ++kc) {
    __syncthreads();
    #pragma unroll
    for (int i = 0; i < 4; ++i) {
      int t = i*256 + tid;
      int m = t >> 4, kq = (t & 15)*4;
      long aoff;
      int r = rt*64 + m;
      if (gather) { int n2 = r / TT, t2 = r - n2*TT; aoff = ((long)t2*NN + n2)*64 + kc*64 + kq; }
      else aoff = (long)r*KD + kc*64 + kq;
      float4 av = ld4f(A + aoff);
      As[kq+0][m] = av.x; As[kq+1][m] = av.y; As[kq+2][m] = av.z; As[kq+3][m] = av.w;
      int col = bcn*64 + m;
      float4 bv = *(const float4*)&B[(long)col*KD + kc*64 + kq];
      Bs[kq+0][m] = bv.x; Bs[kq+1][m] = bv.y; Bs[kq+2][m] = bv.z; Bs[kq+3][m] = bv.w;
    }
    __syncthreads();
    #pragma unroll 8
    for (int kk = 0; kk < 64; ++kk) {
      float4 a4 = *(const float4*)&As[kk][ty*4];
      float4 b4 = *(const float4*)&Bs[kk][tx*4];
      acc[0][0] += a4.x*b4.x; acc[0][1] += a4.x*b4.y; acc[0][2] += a4.x*b4.z; acc[0][3] += a4.x*b4.w;
      acc[1][0] += a4.y*b4.x; acc[1][1] += a4.y*b4.y; acc[1][2] += a4.y*b4.z; acc[1][3] += a4.y*b4.w;
      acc[2][0] += a4.z*b4.x; acc[2][1] += a4.z*b4.y; acc[2][2] += a4.z*b4.z; acc[2][3] += a4.z*b4.w;
      acc[3][0] += a4.w*b4.x; acc[3][1] += a4.w*b4.y; acc[3][2] += a4.w*b4.z; acc[3][3] += a4.w*b4.w;
    }
  }
  float bv[4];
  #pragma unroll
  for (int j = 0; j < 4; ++j) bv[j] = bias ? bias[bcn*64 + tx*4 + j] : 0.f;
  #pragma unroll
  for (int i = 0; i < 4; ++i) {
    long ro = (long)(rt*64 + ty*4 + i)*NC + bcn*64 + tx*4;
    #pragma unroll
    for (int j = 0; j < 4; ++j) stf(C, ro + j, acc[i][j] + bv[j]);
  }
}

// ---------------- GRU recurrence: one block (192 thr) per batch row ----------------
// inner product via float4 LDS reads + 4 partial fp32 sums (tolerant path)
__global__ __launch_bounds__(192) void k_gru(
  const float* __restrict__ gi, const float* __restrict__ whh, const float* __restrict__ bhh,
  bf16* __restrict__ g_out, float* __restrict__ res_out, int layer)
{
  int n = blockIdx.x;
  int tid = threadIdx.x;
  int g = tid >> 6, o = tid & 63;
  __shared__ __align__(16) float h_lds[64];
  __shared__ float ghs[3][64];
  float4 w4[16];
  #pragma unroll
  for (int k4 = 0; k4 < 16; ++k4)
    w4[k4] = *(const float4*)&whh[(long)(g*64+o)*64 + k4*4];
  float bh = bhh[g*64+o];
  if (tid < 64) h_lds[tid] = 0.f;
  __syncthreads();
  const float4* h4 = (const float4*)h_lds;
  for (int t = 0; t < TT; ++t) {
    float p0 = 0.f, p1 = 0.f, p2 = 0.f, p3 = 0.f;
    #pragma unroll
    for (int k4 = 0; k4 < 16; ++k4) {
      float4 hv = h4[k4];
      p0 = fmaf(w4[k4].x, hv.x, p0);
      p1 = fmaf(w4[k4].y, hv.y, p1);
      p2 = fmaf(w4[k4].z, hv.z, p2);
      p3 = fmaf(w4[k4].w, hv.w, p3);
    }
    ghs[g][o] = bh + ((p0 + p1) + (p2 + p3));
    __syncthreads();
    if (tid < 64) {
      const float* gib = gi + ((long)n*TT + t)*192;
      float ir = gib[o], iz = gib[64+o], inn = gib[128+o];
      float r = sgm(ir + ghs[0][o]);
      float z = sgm(iz + ghs[1][o]);
      float nn2 = tanhf(inn + r*ghs[2][o]);
      float hn = (1.f - z)*nn2 + z*h_lds[o];
      h_lds[o] = hn;
      if (layer == 0) g_out[((long)t*NN + n)*64 + o] = f2b(hn);
      else if (t == TT-1) res_out[(long)n*64 + o] = lk(hn);
    }
    __syncthreads();
  }
}

// ---------------- dynamic attention v3 ----------------
// Phase A: np-exact scores; q tile held in 16 float4 REGISTERS (loaded once from
//   global — same values/order as before, kills 64 ds_read_b128/thread/p).
// Pairwise mean: 128-thread float4 version, exact same per-chain sequential order
//   and combine tree as the numpy pairwise emulation.
// Phase B: P@V via mfma_f32_16x16x32_bf16 (unchanged).
// LDS 52288 B => true 3 blocks/CU (54400 rounded to 54784 only allowed 2).
#define MULADD4(QV, KV) \
  v0 = __fadd_rn(v0, __fmul_rn((QV).x, (KV).x)); \
  v1 = __fadd_rn(v1, __fmul_rn((QV).y, (KV).y)); \
  v2 = __fadd_rn(v2, __fmul_rn((QV).z, (KV).z)); \
  v3 = __fadd_rn(v3, __fmul_rn((QV).w, (KV).w));

__global__ __launch_bounds__(256, 3) void k_attn_dyn(
  const float* __restrict__ qkx, const bf16* __restrict__ vvc,
  float* __restrict__ attn_out, float* __restrict__ resid, int tc)
{
  // [0,33280): sc f32[16][520] (A) | vT bf16[32][520] (B)
  // [33280,51712): kt f32[128][36] (A) | p_lds bf16[16][520] @33280..49920 (B)
  // [49920,52096): red f32[2][272] (B epilogue)
  // [51712,52224): ulds f32[128] (A mean; time-disjoint from red)
  // [52224,52288): means f32[16]
  __shared__ __align__(16) char smem[52288];
  float* sc    = (float*)smem;                     // [16][520]
  bf16*  vT    = (bf16*)smem;                      // [32][520]
  float* kt    = (float*)(smem + 33280);           // [128][36]
  bf16*  p_lds = (bf16*)(smem + 33280);            // [16][520]
  float* red   = (float*)(smem + 49920);           // [2][16*17]
  float* ulds  = (float*)(smem + 51712);           // [16][8]
  float* means = (float*)(smem + 52224);           // [16]

  int qt = blockIdx.x, h = blockIdx.y, lt = blockIdx.z;
  int gt = tc*TCH + lt;
  int tid = threadIdx.x, tx = tid & 31, grp = tid >> 5;
  int qbase = grp*2;
  int qce = h*32, kce = 64 + h*32;

  // q rows (qbase, qbase+1) in registers: 16 float4, loaded once
  float4 q0r[8], q1r[8];
  {
    const float* qp = qkx + ((long)(lt*NN + qt*16 + qbase))*128 + qce;
    #pragma unroll
    for (int j = 0; j < 8; ++j) q0r[j] = *(const float4*)(qp + j*4);
    #pragma unroll
    for (int j = 0; j < 8; ++j) q1r[j] = *(const float4*)(qp + 128 + j*4);
  }

  float S[2][16];
  for (int p = 0; p < 4; ++p) {
    __syncthreads();
    for (int i = tid; i < 1024; i += 256) {
      int row = i >> 3, jj = (i & 7) << 2;
      *(float4*)(kt + row*36 + jj) =
        *(const float4*)(qkx + ((long)(lt*NN + p*128 + row))*128 + kce + jj);
    }
    __syncthreads();
    #pragma unroll
    for (int ii = 0; ii < 4; ++ii) {
      int m = tx + 32*ii;
      const float4* kr4 = (const float4*)(kt + m*36);
      float4 k0 = kr4[0], k1 = kr4[1], k2 = kr4[2], k3 = kr4[3];
      float4 k4 = kr4[4], k5 = kr4[5], k6 = kr4[6], k7 = kr4[7];
      // numpy einsum baseline-SIMD emulation: 4 lanes, sequential unfused
      // mul+add per lane over d = l, l+4, ..., l+28; SSE3 hadd tree at end.
      {
        float v0 = 0.f, v1 = 0.f, v2 = 0.f, v3 = 0.f;
        MULADD4(q0r[0], k0); MULADD4(q0r[1], k1); MULADD4(q0r[2], k2); MULADD4(q0r[3], k3);
        MULADD4(q0r[4], k4); MULADD4(q0r[5], k5); MULADD4(q0r[6], k6); MULADD4(q0r[7], k7);
        float s = __fadd_rn(__fadd_rn(v0, v1), __fadd_rn(v2, v3));
        s = s * 0.125f;
        S[0][p*4+ii] = s;
        sc[(qbase+0)*520 + p*128 + m] = s;
      }
      {
        float v0 = 0.f, v1 = 0.f, v2 = 0.f, v3 = 0.f;
        MULADD4(q1r[0], k0); MULADD4(q1r[1], k1); MULADD4(q1r[2], k2); MULADD4(q1r[3], k3);
        MULADD4(q1r[4], k4); MULADD4(q1r[5], k5); MULADD4(q1r[6], k6); MULADD4(q1r[7], k7);
        float s = __fadd_rn(__fadd_rn(v0, v1), __fadd_rn(v2, v3));
        s = s * 0.125f;
        S[1][p*4+ii] = s;
        sc[(qbase+1)*520 + p*128 + m] = s;
      }
    }
  }
  __syncthreads();
  // numpy pairwise mean over 512 per row: 4 base-blocks of 128, 8 strided
  // accumulators each — exact order preserved; 128 threads, float4 reads.
  if (tid < 128) {
    int row = tid >> 3, b = (tid >> 1) & 3, hh = tid & 1;
    const float* a = sc + row*520 + b*128 + hh*4;
    float4 r4 = *(const float4*)a;
    #pragma unroll
    for (int i = 8; i < 128; i += 8) {
      float4 v = *(const float4*)(a + i);
      r4.x = __fadd_rn(r4.x, v.x); r4.y = __fadd_rn(r4.y, v.y);
      r4.z = __fadd_rn(r4.z, v.z); r4.w = __fadd_rn(r4.w, v.w);
    }
    ulds[row*8 + b*2 + hh] = __fadd_rn(__fadd_rn(r4.x, r4.y), __fadd_rn(r4.z, r4.w));
  }
  __syncthreads();
  if (tid < 16) {
    const float* ur = ulds + tid*8;
    float p0 = __fadd_rn(ur[0], ur[1]);
    float p1 = __fadd_rn(ur[2], ur[3]);
    float p2 = __fadd_rn(ur[4], ur[5]);
    float p3 = __fadd_rn(ur[6], ur[7]);
    means[tid] = __fadd_rn(__fadd_rn(p0, p1), __fadd_rn(p2, p3)) * (1.f/512.f);
  }
  __syncthreads();

  long obase = ((long)(gt*2 + h))*NN*NN;
  #pragma unroll
  for (int qi = 0; qi < 2; ++qi) {
    float mn = means[qbase + qi];
    unsigned kmask = 0; float lm = -INFINITY;
    #pragma unroll
    for (int ig = 0; ig < 16; ++ig) {
      if (S[qi][ig] >= mn) { kmask |= (1u << ig); lm = fmaxf(lm, S[qi][ig]); }
    }
    #pragma unroll
    for (int mk = 1; mk < 32; mk <<= 1) lm = fmaxf(lm, __shfl_xor(lm, mk, 64));
    float e[16]; float se = 0.f;
    #pragma unroll
    for (int ig = 0; ig < 16; ++ig) {
      e[ig] = ((kmask >> ig) & 1u) ? __expf(S[qi][ig] - lm) : 0.f;
      se += e[ig];
    }
    #pragma unroll
    for (int mk = 1; mk < 32; mk <<= 1) se += __shfl_xor(se, mk, 64);
    float inv = 1.f/se;
    float* rowp = attn_out + obase + (long)(qt*16 + qbase + qi)*NN;
    bf16* prow = p_lds + (qbase + qi)*520;
    #pragma unroll
    for (int ig = 0; ig < 16; ++ig) {
      float pr = e[ig]*inv;
      rowp[tx + 32*ig] = pr;
      prow[tx + 32*ig] = f2b(pr);
    }
  }

  // stage V transposed: vT[col][k], paired rows packed into dword writes
  for (int i = tid; i < 2048; i += 256) {
    int m2 = (i & 255) << 1;          // k rows m2, m2+1
    int cc = (i >> 8) << 2;           // col base
    const bf16* gp = vvc + ((long)(lt*NN + m2))*128 + qce + cc;
    ushort4 a = *(const ushort4*)(gp);
    ushort4 b = *(const ushort4*)(gp + 128);
    *(unsigned*)(vT + (cc+0)*520 + m2) = (unsigned)a.x | ((unsigned)b.x << 16);
    *(unsigned*)(vT + (cc+1)*520 + m2) = (unsigned)a.y | ((unsigned)b.y << 16);
    *(unsigned*)(vT + (cc+2)*520 + m2) = (unsigned)a.z | ((unsigned)b.z << 16);
    *(unsigned*)(vT + (cc+3)*520 + m2) = (unsigned)a.w | ((unsigned)b.w << 16);
  }
  __syncthreads();

  // phase B: O = P @ V via MFMA. wave w: col-tile nh=w&1, K-half kh=w>>1
  {
    int w = tid >> 6, l = tid & 63;
    int nh = w & 1, kh = w >> 1;
    int arow = l & 15, kgrp = l >> 4;
    facc4 acc = {0.f, 0.f, 0.f, 0.f};
    const bf16* pa = p_lds + arow*520 + kh*256 + kgrp*8;
    const bf16* pb = vT + (nh*16 + arow)*520 + kh*256 + kgrp*8;
    #pragma unroll
    for (int ks = 0; ks < 8; ++ks) {
      bfrag8 av = *(const bfrag8*)(pa + ks*32);
      bfrag8 bv = *(const bfrag8*)(pb + ks*32);
      acc = __builtin_amdgcn_mfma_f32_16x16x32_bf16(av, bv, acc, 0, 0, 0);
    }
    if (w >= 2) {
      #pragma unroll
      for (int r = 0; r < 4; ++r)
        red[nh*272 + (kgrp*4 + r)*17 + arow] = acc[r];
    }
    __syncthreads();
    if (w < 2) {
      long rb = ((long)gt*NN + qt*16)*64 + h*32 + nh*16 + arow;
      #pragma unroll
      for (int r = 0; r < 4; ++r) {
        int row = kgrp*4 + r;
        resid[rb + (long)row*64] += acc[r] + red[nh*272 + row*17 + arow];
      }
    }
  }
}

// ---------------- static attention v2 (fp32 scores, adjacency bitmask) ----------------
__global__ __launch_bounds__(256, 3) void k_attn_st(
  const float* __restrict__ qkc, const bf16* __restrict__ vvc,
  const unsigned int* __restrict__ msk, float* __restrict__ resid, int tc)
{
  // R0 [0,34816): kc f32[128][68] swizzled (phase A) | vTh bf16[64][264] (phase B)
  // R1 [34816,51456): q f32[16][68] (phase A) | P bf16[16][520] (phase B)
  __shared__ __align__(16) char smem[51456];
  float* kc  = (float*)smem;                 // [128][68] f32 (swizzled float4 units)
  bf16*  vTh = (bf16*)smem;                  // [64][264] bf16 (K-half of V^T)
  float* qtl = (float*)(smem + 34816);       // [16][68] f32
  bf16*  P   = (bf16*)(smem + 34816);        // [16][520] bf16 (overlays qtl after use)

  int qt = blockIdx.x, lt = blockIdx.z;
  int gt = tc*TCH + lt;
  int tid = threadIdx.x;
  int tx = tid & 31, grp = tid >> 5;
  int qbase = grp*2;

  float4* q4 = (float4*)qtl;    // stride 17 float4
  float4* k4 = (float4*)kc;     // stride 17 float4

  // stage q tile [16][64] f32 (1 float4 per thread, coalesced)
  {
    int m = tid >> 4, jc = tid & 15;
    q4[m*17 + jc] = *(const float4*)(qkc + ((long)(lt*NN + qt*16 + m))*128 + jc*4);
  }

  float S[2][16];
  for (int p = 0; p < 4; ++p) {
    __syncthreads();
    // stage kc chunk [128][64] f32, XOR-swizzled float4 units
    for (int i = tid; i < 2048; i += 256) {
      int m = i >> 4, jc = i & 15;
      k4[m*17 + (jc ^ ((m >> 2) & 3))] =
        *(const float4*)(qkc + ((long)(lt*NN + p*128 + m))*128 + 64 + jc*4);
    }
    __syncthreads();
    float acc00 = 0.f, acc01 = 0.f, acc02 = 0.f, acc03 = 0.f;
    float acc10 = 0.f, acc11 = 0.f, acc12 = 0.f, acc13 = 0.f;
    #pragma unroll 4
    for (int jc = 0; jc < 16; ++jc) {
      float4 q0 = q4[(qbase+0)*17 + jc];
      float4 q1 = q4[(qbase+1)*17 + jc];
      float4 kv;
      int m0 = tx;
      kv = k4[m0*17 + (jc ^ ((m0 >> 2) & 3))];
      acc00 += q0.x*kv.x + q0.y*kv.y + q0.z*kv.z + q0.w*kv.w;
      acc10 += q1.x*kv.x + q1.y*kv.y + q1.z*kv.z + q1.w*kv.w;
      int m1 = tx + 32;
      kv = k4[m1*17 + (jc ^ ((m1 >> 2) & 3))];
      acc01 += q0.x*kv.x + q0.y*kv.y + q0.z*kv.z + q0.w*kv.w;
      acc11 += q1.x*kv.x + q1.y*kv.y + q1.z*kv.z + q1.w*kv.w;
      int m2 = tx + 64;
      kv = k4[m2*17 + (jc ^ ((m2 >> 2) & 3))];
      acc02 += q0.x*kv.x + q0.y*kv.y + q0.z*kv.z + q0.w*kv.w;
      acc12 += q1.x*kv.x + q1.y*kv.y + q1.z*kv.z + q1.w*kv.w;
      int m3 = tx + 96;
      kv = k4[m3*17 + (jc ^ ((m3 >> 2) & 3))];
      acc03 += q0.x*kv.x + q0.y*kv.y + q0.z*kv.z + q0.w*kv.w;
      acc13 += q1.x*kv.x + q1.y*kv.y + q1.z*kv.z + q1.w*kv.w;
    }
    S[0][p*4+0] = acc00; S[0][p*4+1] = acc01; S[0][p*4+2] = acc02; S[0][p*4+3] = acc03;
    S[1][p*4+0] = acc10; S[1][p*4+1] = acc11; S[1][p*4+2] = acc12; S[1][p*4+3] = acc13;
  }
  __syncthreads();   // kc + qtl dead after this point

  // scale + mask + softmax (fp32, register-resident)
  #pragma unroll
  for (int qi = 0; qi < 2; ++qi) {
    #pragma unroll
    for (int ig = 0; ig < 16; ++ig) S[qi][ig] *= SCALEV;
    float lm = -INFINITY;
    #pragma unroll
    for (int ig = 0; ig < 16; ++ig) {
      bool keep = ((msk[(qt*16 + qbase + qi)*16 + ig] >> tx) & 1u) != 0u;
      float v = keep ? S[qi][ig] : NEGV;
      S[qi][ig] = v;
      lm = fmaxf(lm, v);
    }
    #pragma unroll
    for (int mk = 1; mk < 32; mk <<= 1) lm = fmaxf(lm, __shfl_xor(lm, mk, 64));
    float se = 0.f;
    #pragma unroll
    for (int ig = 0; ig < 16; ++ig) {
      float ev = __expf(S[qi][ig] - lm);
      S[qi][ig] = ev;
      se += ev;
    }
    #pragma unroll
    for (int mk = 1; mk < 32; mk <<= 1) se += __shfl_xor(se, mk, 64);
    float inv = 1.f / se;
    bf16* prow = P + (qbase + qi)*520;
    #pragma unroll
    for (int ig = 0; ig < 16; ++ig)
      prow[tx + 32*ig] = f2b(S[qi][ig]*inv);
  }

  // phase B: O = P @ V via MFMA; K in two 256-halves, wave w = col-tile
  int w = tid >> 6, l = tid & 63;
  int arow = l & 15, kgrp = l >> 4;
  facc4 acc = {0.f, 0.f, 0.f, 0.f};
  for (int kh = 0; kh < 2; ++kh) {
    __syncthreads();
    // stage V^T half: vTh[col][k-kh*256], paired k-rows packed into dwords
    for (int i = tid; i < 2048; i += 256) {
      int m2 = (i & 127) << 1;          // local k rows m2, m2+1
      int cc = (i >> 7) << 2;           // col base
      const bf16* gp = vvc + ((long)(lt*NN + kh*256 + m2))*128 + 64 + cc;
      ushort4 a = *(const ushort4*)(gp);
      ushort4 b = *(const ushort4*)(gp + 128);
      *(unsigned*)(vTh + (cc+0)*264 + m2) = (unsigned)a.x | ((unsigned)b.x << 16);
      *(unsigned*)(vTh + (cc+1)*264 + m2) = (unsigned)a.y | ((unsigned)b.y << 16);
      *(unsigned*)(vTh + (cc+2)*264 + m2) = (unsigned)a.z | ((unsigned)b.z << 16);
      *(unsigned*)(vTh + (cc+3)*264 + m2) = (unsigned)a.w | ((unsigned)b.w << 16);
    }
    __syncthreads();
    const bf16* pa = P + arow*520 + kh*256 + kgrp*8;
    const bf16* pb = vTh + (w*16 + arow)*264 + kgrp*8;
    #pragma unroll
    for (int ks = 0; ks < 8; ++ks) {
      bfrag8 av = *(const bfrag8*)(pa + ks*32);
      bfrag8 bv = *(const bfrag8*)(pb + ks*32);
      acc = __builtin_amdgcn_mfma_f32_16x16x32_bf16(av, bv, acc, 0, 0, 0);
    }
  }
  // epilogue: C/D map col=lane&15, row=(lane>>4)*4+r
  long rb = ((long)gt*NN + qt*16)*64 + w*16 + arow;
  #pragma unroll
  for (int r = 0; r < 4; ++r) {
    int row = kgrp*4 + r;
    resid[rb + (long)row*64] += acc[r];
  }
}

// ---------------- LN1 ----------------
__global__ __launch_bounds__(256) void k_ln1(
  const float* __restrict__ resid, const float* __restrict__ gw, const float* __restrict__ bw,
  float* __restrict__ ln1o)
{
  int lane = threadIdx.x & 63;
  long r = (long)blockIdx.x*4 + (threadIdx.x >> 6);
  long base = r*64 + lane;
  float v = resid[base];
  float m = wsum64(v)*(1.f/64.f);
  float d = v - m;
  float var = wsum64(d*d)*(1.f/64.f);
  ln1o[base] = d*rsqrtf(var + 1e-5f)*gw[lane] + bw[lane];
}

// ---------------- LN2 + leaky + PE -> src ----------------
__global__ __launch_bounds__(256) void k_ln2_src(
  const float* __restrict__ mlpo, const float* __restrict__ resid,
  const float* __restrict__ gw, const float* __restrict__ bw,
  float* __restrict__ src)
{
  int lane = threadIdx.x & 63;
  long r = (long)blockIdx.x*4 + (threadIdx.x >> 6);
  long base = r*64 + lane;
  float v = mlpo[base] + resid[base];
  float m = wsum64(v)*(1.f/64.f);
  float d = v - m;
  float var = wsum64(d*d)*(1.f/64.f);
  float y = d*rsqrtf(var + 1e-5f)*gw[lane] + bw[lane];
  y = lk(y);
  float tf = (float)(r / NN);
  float dv = __expf(-(float)(lane & ~1) * 0.14391156831212787f);
  float pe = (lane & 1) ? cosf(tf*dv) : sinf(tf*dv);
  src[base] = y + pe;
}

// ---------------- head ----------------
__global__ __launch_bounds__(64) void k_head(
  const bf16* __restrict__ mqkv, const float* __restrict__ rts,
  const float* __restrict__ mow, const float* __restrict__ mob,
  const float* __restrict__ xsw, const float* __restrict__ xtw, const float* __restrict__ xtb,
  const float* __restrict__ hw, const float* __restrict__ hb,
  const float* __restrict__ linw, const float* __restrict__ linb,
  float* __restrict__ out)
{
  int n = blockIdx.x, o = threadIdx.x;
  __shared__ float ps[TT];
  __shared__ float buf[64], buf2[64];
  float mq = b2f(mqkv[((long)(TT-1)*NN + n)*192 + o]);
  for (int s = 0; s < TT; ++s) {
    float v = mq * b2f(mqkv[((long)s*NN + n)*192 + 64 + o]);
    v = wsum64(v);
    if (o == 0) ps[s] = v * SCALEV;
  }
  __syncthreads();
  float x = (o < TT) ? ps[o] : -INFINITY;
  float mx = wmax64(x);
  float e = (o < TT) ? __expf(x - mx) : 0.f;
  float se = wsum64(e);
  if (o < TT) ps[o] = e / se;
  __syncthreads();
  float acc = 0.f;
  for (int s = 0; s < TT; ++s) acc += ps[s]*b2f(mqkv[((long)s*NN + n)*192 + 128 + o]);
  buf[o] = acc;
  __syncthreads();
  float acc2 = mob[o];
  for (int k = 0; k < 64; ++k) acc2 += buf[k]*mow[o*64 + k];
  float m2 = wsum64(acc2)*(1.f/64.f);
  float d2 = acc2 - m2;
  float var2 = wsum64(d2*d2)*(1.f/64.f);
  float a = d2*rsqrtf(var2 + 1e-5f);
  float rt = rts[(long)n*64 + o];
  __syncthreads();
  buf[o] = a; buf2[o] = rt;
  __syncthreads();
  float pre = xtb[o];
  for (int k = 0; k < 64; ++k) pre += buf[k]*xsw[o*64 + k] + buf2[k]*xtw[o*64 + k];
  float zg = sgm(pre);
  float u = zg*a + (1.f - zg)*rt;
  __syncthreads();
  buf[o] = u;
  __syncthreads();
  float f = hb[o];
  for (int k = 0; k < 64; ++k) f += buf[k]*hw[o*64 + k];
  f = lk(f);
  float tot = wsum64(f * linw[o]);
  if (o == 0) out[n] = tot + linb[0];
}

// =======================================================================
extern "C" void kernel_launch(void* const* d_in, const int* in_sizes, int n_in,
                              void* d_out, int out_size, void* d_ws, size_t ws_size,
                              hipStream_t stream)
{
  const float* x    = (const float*)d_in[0];
  const int*   ei   = (const int*)  d_in[1];
  const float* fcw  = (const float*)d_in[2];
  const float* fcb  = (const float*)d_in[3];
  const float* wih0 = (const float*)d_in[4];
  const float* whh0 = (const float*)d_in[5];
  const float* bih0 = (const float*)d_in[6];
  const float* bhh0 = (const float*)d_in[7];
  const float* wih1 = (const float*)d_in[8];
  const float* whh1 = (const float*)d_in[9];
  const float* bih1 = (const float*)d_in[10];
  const float* bhh1 = (const float*)d_in[11];
  const float* dmqw = (const float*)d_in[12];
  const float* dmkw = (const float*)d_in[13];
  const float* dmvw = (const float*)d_in[14];
  const float* dmvb = (const float*)d_in[15];
  const float* ssqw = (const float*)d_in[16];
  const float* sskw = (const float*)d_in[17];
  const float* ssvw = (const float*)d_in[18];
  const float* ssvb = (const float*)d_in[19];
  const float* ln1g = (const float*)d_in[20];
  const float* ln1b = (const float*)d_in[21];
  const float* ln2g = (const float*)d_in[22];
  const float* ln2b = (const float*)d_in[23];
  const float* mw1  = (const float*)d_in[24];
  const float* mb1  = (const float*)d_in[25];
  const float* mw2  = (const float*)d_in[26];
  const float* mb2  = (const float*)d_in[27];
  const float* mhw  = (const float*)d_in[28];
  const float* mhb  = (const float*)d_in[29];
  const float* mow  = (const float*)d_in[30];
  const float* mob  = (const float*)d_in[31];
  const float* gxsw = (const float*)d_in[32];
  const float* gxtw = (const float*)d_in[33];
  const float* gxtb = (const float*)d_in[34];
  const float* ghw  = (const float*)d_in[35];
  const float* ghb  = (const float*)d_in[36];
  const float* linw = (const float*)d_in[37];
  const float* linb = (const float*)d_in[38];

  // ---- workspace layout (~43.6 MB envelope, unchanged) ----
  char* base = (char*)d_ws;
  float*  xs    = (float*)(base);                 // xs f32; later mlpo f32
  char*   Rb    = base + 7864320;                 // shared region (15.73 MB):
  float*  qkc   = (float*)Rb;                     //   per-chunk qs|ks f32 (5.24MB, TCH=20)
  bf16*   vvc   = (bf16*)(Rb + 5242880);          //   per-chunk v|vs bf16 (2.62MB)
  float*  qkx   = (float*)(Rb + 7864320);         //   per-chunk exact q|k f32 (5.24MB)
  float*  mlph  = (float*)Rb;                     //   later: mlp hidden f32 (15.73MB)
  bf16*   mqkv  = (bf16*)Rb;                      //   later: mha qkv bf16 (11.8MB)
  bf16*   g0    = (bf16*)(base + 23592960);
  float*  resid = (float*)(base + 27525120);
  float*  ln1o  = (float*)(base + 35389440);
  float*  rts   = (float*)(base + 43253760);
  unsigned int* msk = (unsigned int*)(base + 43384832);
  float*  Wall  = (float*)(base + 43417600);      // 6*4096 f32 (q|k|qs|ks|v|vs)
  float*  bcV   = (float*)(base + 43515904);      // 128 f32
  float*  mlpo  = xs;
  float*  src   = ln1o;
  float*  outb  = (float*)d_out;
  float*  attn  = outb + 512;
  // gi staged in d_out's attn region — dead before k_attn_dyn writes probs
  float*  gi    = (float*)((char*)d_out + 2048);

  k_zero_u32<<<dim3(32), 256, 0, stream>>>(msk, 512*16);
  k_scatter_bits<<<dim3(32), 256, 0, stream>>>(ei, msk);
  k_pack<<<dim3(97), 256, 0, stream>>>(dmqw, dmkw, ssqw, sskw, dmvw, ssvw, dmvb, ssvb, Wall, bcV);
  k_fcin<<<dim3(TN*64/256), 256, 0, stream>>>(x, fcw, fcb, xs, resid);
  // GRU layer 0
  k_gemm<float,float><<<dim3(480, 3), 256, 0, stream>>>(xs, wih0, bih0, gi, 64, 192, 1);
  k_gru<<<dim3(NN), 192, 0, stream>>>(gi, whh0, bhh0, g0, nullptr, 0);
  // GRU layer 1
  k_gemm<bf16,float><<<dim3(480, 3), 256, 0, stream>>>(g0, wih1, bih1, gi, 64, 192, 1);
  k_gru<<<dim3(NN), 192, 0, stream>>>(gi, whh1, bhh1, nullptr, rts, 1);
  // attention in 3 t-chunks of 20
  for (int tc = 0; tc < NCHK; ++tc) {
    const float* xsc = xs + (size_t)tc*TCH*NN*64;
    k_proj<<<dim3(TCH*NN/64, 6), 256, 0, stream>>>(xsc, Wall, bcV, qkx, qkc, vvc);
    k_attn_dyn<<<dim3(32, 2, TCH), 256, 0, stream>>>(qkx, vvc, attn, resid, tc);
    k_attn_st <<<dim3(32, 1, TCH), 256, 0, stream>>>(qkc, vvc, msk, resid, tc);
  }
  // LN1 -> MLP -> LN2+PE
  k_ln1<<<dim3(TN/4), 256, 0, stream>>>(resid, ln1g, ln1b, ln1o);
  k_gemm<float,float><<<dim3(480, 2), 256, 0, stream>>>(ln1o, mw1, mb1, mlph, 64, 128, 0);
  k_gemm<float,float><<<dim3(480, 1), 256, 0, stream>>>(mlph, mw2, mb2, mlpo, 128, 64, 0);
  k_ln2_src<<<dim3(TN/4), 256, 0, stream>>>(mlpo, resid, ln2g, ln2b, src);
  // mha in-projection + head
  k_gemm<float,bf16 ><<<dim3(480, 3), 256, 0, stream>>>(src, mhw, mhb, mqkv, 64, 192, 0);
  k_head<<<dim3(NN), 64, 0, stream>>>(mqkv, rts, mow, mob, gxsw, gxtw, gxtb, ghw, ghb, linw, linb, outb);
}

// Round 5
// 732.337 us; speedup vs baseline: 1.9749x; 1.0027x over previous
//
#include <hip/hip_runtime.h>
#include <hip/hip_bf16.h>

#define NN 512
#define TT 60
#define DFF 6
#define EE 8192
#define TN (TT*NN)
#define TCH 20          // t-chunk size
#define NCHK 3          // number of t-chunks
#define SCALEV 0.125f
#define NEGV -1.0e10f

typedef __hip_bfloat16 bf16;
using bfrag8 = __attribute__((ext_vector_type(8))) short;   // 8 bf16 (4 VGPRs)
using facc4  = __attribute__((ext_vector_type(4))) float;   // 4 f32 acc

__device__ __forceinline__ float b2f(bf16 v){ return __bfloat162float(v); }
__device__ __forceinline__ bf16 f2b(float v){ return __float2bfloat16(v); }
__device__ __forceinline__ float lk(float x){ return x >= 0.f ? x : 0.01f*x; }
__device__ __forceinline__ float sgm(float x){ return 1.f/(1.f+__expf(-x)); }

__device__ __forceinline__ float ldf(const float* p, long i){ return p[i]; }
__device__ __forceinline__ float ldf(const bf16* p, long i){ return b2f(p[i]); }
__device__ __forceinline__ void stf(float* p, long i, float v){ p[i] = v; }
__device__ __forceinline__ void stf(bf16* p, long i, float v){ p[i] = f2b(v); }

__device__ __forceinline__ float4 ld4f(const float* p){ return *(const float4*)p; }
__device__ __forceinline__ float4 ld4f(const bf16* p){
  ushort4 u = *(const ushort4*)p;
  float4 f;
  f.x = b2f(*(const bf16*)&u.x);
  f.y = b2f(*(const bf16*)&u.y);
  f.z = b2f(*(const bf16*)&u.z);
  f.w = b2f(*(const bf16*)&u.w);
  return f;
}

__device__ __forceinline__ float wsum64(float v){
  #pragma unroll
  for (int off = 32; off; off >>= 1) v += __shfl_xor(v, off, 64);
  return v;
}
__device__ __forceinline__ float wmax64(float v){
  #pragma unroll
  for (int off = 32; off; off >>= 1) v = fmaxf(v, __shfl_xor(v, off, 64));
  return v;
}

// ---------------- pack (blocks 0..96) + adjacency bitmask (block 97, LDS atomics) ----
__global__ __launch_bounds__(256) void k_pack(
  const float* __restrict__ qw, const float* __restrict__ kw,
  const float* __restrict__ qsw, const float* __restrict__ ksw,
  const float* __restrict__ vw, const float* __restrict__ vsw,
  const float* __restrict__ vb, const float* __restrict__ vsb,
  const int* __restrict__ ei, unsigned int* __restrict__ msk,
  float* __restrict__ Wall, float* __restrict__ bcV)
{
  __shared__ unsigned int lmsk[8192];
  int tid = threadIdx.x;
  if (blockIdx.x == 97) {
    for (int i = tid; i < 8192; i += 256) lmsk[i] = 0u;
    __syncthreads();
    for (int e = tid; e < EE; e += 256) {
      int u = ei[e], v = ei[EE + e];
      atomicOr(&lmsk[u*16 + (v >> 5)], 1u << (v & 31));
    }
    __syncthreads();
    for (int i = tid; i < 8192; i += 256) msk[i] = lmsk[i];
    return;
  }
  int idx = blockIdx.x*256 + tid;
  if (idx < 6*4096) {
    int which = idx >> 12, rem = idx & 4095;
    const float* s = (which==0)?qw:(which==1)?kw:(which==2)?qsw:(which==3)?ksw:(which==4)?vw:vsw;
    Wall[idx] = s[rem];
  } else if (idx < 6*4096 + 128) {
    int o = idx - 6*4096;
    bcV[o] = (o < 64) ? vb[o] : vsb[o-64];
  }
}

// ---------------- fc_in: np-exact fp32 (seq-FMA over k, bias added after) ----------------
__global__ __launch_bounds__(256) void k_fcin(
  const float* __restrict__ x, const float* __restrict__ w, const float* __restrict__ b,
  float* __restrict__ xs, float* __restrict__ resid)
{
  long idx = (long)blockIdx.x*256 + threadIdx.x;   // < TN*64
  int o = idx & 63;
  long r = idx >> 6;                // r = t*NN + n
  int t = (int)(r / NN), n = (int)(r % NN);
  const float* xr = x + ((long)n*TT + t)*DFF;
  const float* wr = w + o*DFF;
  float acc = 0.f;
  #pragma unroll
  for (int j = 0; j < DFF; ++j) acc = fmaf(xr[j], wr[j], acc);
  float h = __fadd_rn(acc, b[o]);
  xs[idx] = h;
  resid[idx] = h;
}

// ---------------- fused per-chunk projection (np-exact seq-FMA over k=0..63) ----------------
__global__ __launch_bounds__(256) void k_proj(
  const float* __restrict__ A, const float* __restrict__ Wall, const float* __restrict__ bcV,
  float* __restrict__ qkx, float* __restrict__ qkc, bf16* __restrict__ vvc)
{
  __shared__ float As[64][68];
  __shared__ float Bs[64][68];
  int rt = blockIdx.x, bcn = blockIdx.y;
  const float* B = Wall + bcn*4096;
  int tid = threadIdx.x;
  int tx = tid & 15, ty = tid >> 4;
  float acc[4][4] = {{0.f}};
  #pragma unroll
  for (int i = 0; i < 4; ++i) {
    int t = i*256 + tid;
    int m = t >> 4, kq = (t & 15)*4;
    float4 av = *(const float4*)&A[(long)(rt*64 + m)*64 + kq];
    As[kq+0][m] = av.x; As[kq+1][m] = av.y; As[kq+2][m] = av.z; As[kq+3][m] = av.w;
    float4 bv = *(const float4*)&B[(long)m*64 + kq];
    Bs[kq+0][m] = bv.x; Bs[kq+1][m] = bv.y; Bs[kq+2][m] = bv.z; Bs[kq+3][m] = bv.w;
  }
  __syncthreads();
  for (int kk = 0; kk < 64; ++kk) {
    float4 a4 = *(const float4*)&As[kk][ty*4];
    float4 b4 = *(const float4*)&Bs[kk][tx*4];
    acc[0][0] = fmaf(a4.x,b4.x,acc[0][0]); acc[0][1] = fmaf(a4.x,b4.y,acc[0][1]); acc[0][2] = fmaf(a4.x,b4.z,acc[0][2]); acc[0][3] = fmaf(a4.x,b4.w,acc[0][3]);
    acc[1][0] = fmaf(a4.y,b4.x,acc[1][0]); acc[1][1] = fmaf(a4.y,b4.y,acc[1][1]); acc[1][2] = fmaf(a4.y,b4.z,acc[1][2]); acc[1][3] = fmaf(a4.y,b4.w,acc[1][3]);
    acc[2][0] = fmaf(a4.z,b4.x,acc[2][0]); acc[2][1] = fmaf(a4.z,b4.y,acc[2][1]); acc[2][2] = fmaf(a4.z,b4.z,acc[2][2]); acc[2][3] = fmaf(a4.z,b4.w,acc[2][3]);
    acc[3][0] = fmaf(a4.w,b4.x,acc[3][0]); acc[3][1] = fmaf(a4.w,b4.y,acc[3][1]); acc[3][2] = fmaf(a4.w,b4.z,acc[3][2]); acc[3][3] = fmaf(a4.w,b4.w,acc[3][3]);
  }
  if (bcn < 4) {
    float* C = (bcn < 2) ? qkx : qkc;
    int cb = (bcn & 1)*64;
    #pragma unroll
    for (int i = 0; i < 4; ++i) {
      long ro = (long)(rt*64 + ty*4 + i)*128 + cb + tx*4;
      #pragma unroll
      for (int j = 0; j < 4; ++j) C[ro + j] = acc[i][j];
    }
  } else {
    int cb = (bcn - 4)*64;
    float bv[4];
    #pragma unroll
    for (int j = 0; j < 4; ++j) bv[j] = bcV[cb + tx*4 + j];
    #pragma unroll
    for (int i = 0; i < 4; ++i) {
      long ro = (long)(rt*64 + ty*4 + i)*128 + cb + tx*4;
      #pragma unroll
      for (int j = 0; j < 4; ++j) vvc[ro + j] = f2b(acc[i][j] + bv[j]);
    }
  }
}

// ---------------- generic projection GEMM (fp32, tolerant paths) ----------------
template<typename TA, typename TC>
__global__ __launch_bounds__(256) void k_gemm(
  const TA* __restrict__ A, const float* __restrict__ B, const float* __restrict__ bias,
  TC* __restrict__ C, int KD, int NC, int gather)
{
  __shared__ float As[64][68];
  __shared__ float Bs[64][68];
  int rt = blockIdx.x, bcn = blockIdx.y;
  int tid = threadIdx.x;
  int tx = tid & 15, ty = tid >> 4;
  float acc[4][4] = {{0.f}};
  int nch = KD >> 6;
  for (int kc = 0; kc < nch; ++kc) {
    __syncthreads();
    #pragma unroll
    for (int i = 0; i < 4; ++i) {
      int t = i*256 + tid;
      int m = t >> 4, kq = (t & 15)*4;
      long aoff;
      int r = rt*64 + m;
      if (gather) { int n2 = r / TT, t2 = r - n2*TT; aoff = ((long)t2*NN + n2)*64 + kc*64 + kq; }
      else aoff = (long)r*KD + kc*64 + kq;
      float4 av = ld4f(A + aoff);
      As[kq+0][m] = av.x; As[kq+1][m] = av.y; As[kq+2][m] = av.z; As[kq+3][m] = av.w;
      int col = bcn*64 + m;
      float4 bv = *(const float4*)&B[(long)col*KD + kc*64 + kq];
      Bs[kq+0][m] = bv.x; Bs[kq+1][m] = bv.y; Bs[kq+2][m] = bv.z; Bs[kq+3][m] = bv.w;
    }
    __syncthreads();
    #pragma unroll 8
    for (int kk = 0; kk < 64; ++kk) {
      float4 a4 = *(const float4*)&As[kk][ty*4];
      float4 b4 = *(const float4*)&Bs[kk][tx*4];
      acc[0][0] += a4.x*b4.x; acc[0][1] += a4.x*b4.y; acc[0][2] += a4.x*b4.z; acc[0][3] += a4.x*b4.w;
      acc[1][0] += a4.y*b4.x; acc[1][1] += a4.y*b4.y; acc[1][2] += a4.y*b4.z; acc[1][3] += a4.y*b4.w;
      acc[2][0] += a4.z*b4.x; acc[2][1] += a4.z*b4.y; acc[2][2] += a4.z*b4.z; acc[2][3] += a4.z*b4.w;
      acc[3][0] += a4.w*b4.x; acc[3][1] += a4.w*b4.y; acc[3][2] += a4.w*b4.z; acc[3][3] += a4.w*b4.w;
    }
  }
  float bv[4];
  #pragma unroll
  for (int j = 0; j < 4; ++j) bv[j] = bias ? bias[bcn*64 + tx*4 + j] : 0.f;
  #pragma unroll
  for (int i = 0; i < 4; ++i) {
    long ro = (long)(rt*64 + ty*4 + i)*NC + bcn*64 + tx*4;
    #pragma unroll
    for (int j = 0; j < 4; ++j) stf(C, ro + j, acc[i][j] + bv[j]);
  }
}

// ---------------- GRU recurrence: one block (192 thr) per batch row ----------------
__global__ __launch_bounds__(192) void k_gru(
  const float* __restrict__ gi, const float* __restrict__ whh, const float* __restrict__ bhh,
  bf16* __restrict__ g_out, float* __restrict__ res_out, int layer)
{
  int n = blockIdx.x;
  int tid = threadIdx.x;
  int g = tid >> 6, o = tid & 63;
  __shared__ __align__(16) float h_lds[64];
  __shared__ float ghs[3][64];
  float4 w4[16];
  #pragma unroll
  for (int k4 = 0; k4 < 16; ++k4)
    w4[k4] = *(const float4*)&whh[(long)(g*64+o)*64 + k4*4];
  float bh = bhh[g*64+o];
  if (tid < 64) h_lds[tid] = 0.f;
  __syncthreads();
  const float4* h4 = (const float4*)h_lds;
  for (int t = 0; t < TT; ++t) {
    float p0 = 0.f, p1 = 0.f, p2 = 0.f, p3 = 0.f;
    #pragma unroll
    for (int k4 = 0; k4 < 16; ++k4) {
      float4 hv = h4[k4];
      p0 = fmaf(w4[k4].x, hv.x, p0);
      p1 = fmaf(w4[k4].y, hv.y, p1);
      p2 = fmaf(w4[k4].z, hv.z, p2);
      p3 = fmaf(w4[k4].w, hv.w, p3);
    }
    ghs[g][o] = bh + ((p0 + p1) + (p2 + p3));
    __syncthreads();
    if (tid < 64) {
      const float* gib = gi + ((long)n*TT + t)*192;
      float ir = gib[o], iz = gib[64+o], inn = gib[128+o];
      float r = sgm(ir + ghs[0][o]);
      float z = sgm(iz + ghs[1][o]);
      float nn2 = tanhf(inn + r*ghs[2][o]);
      float hn = (1.f - z)*nn2 + z*h_lds[o];
      h_lds[o] = hn;
      if (layer == 0) g_out[((long)t*NN + n)*64 + o] = f2b(hn);
      else if (t == TT-1) res_out[(long)n*64 + o] = lk(hn);
    }
    __syncthreads();
  }
}

// ---------------- merged attention: blockIdx.y 0,1 = dynamic head; 2 = static ----------------
// dyn: np-exact scores (q in registers), exact pairwise mean, mask, softmax;
//      P@V via mfma_f32_16x16x32_bf16. LDS layout 52288 B => 3 blocks/CU.
// st : fp32 scores (XOR-swizzled k tile), adjacency mask softmax, MFMA P@V.
#define MULADD4(QV, KV) \
  v0 = __fadd_rn(v0, __fmul_rn((QV).x, (KV).x)); \
  v1 = __fadd_rn(v1, __fmul_rn((QV).y, (KV).y)); \
  v2 = __fadd_rn(v2, __fmul_rn((QV).z, (KV).z)); \
  v3 = __fadd_rn(v3, __fmul_rn((QV).w, (KV).w));

__global__ __launch_bounds__(256, 3) void k_attn(
  const float* __restrict__ qkx, const float* __restrict__ qkc,
  const bf16* __restrict__ vvc, const unsigned int* __restrict__ msk,
  float* __restrict__ attn_out, float* __restrict__ resid, int tc)
{
  __shared__ __align__(16) char smem[52288];
  int qt = blockIdx.x, lt = blockIdx.z;
  int gt = tc*TCH + lt;
  int tid = threadIdx.x, tx = tid & 31, grp = tid >> 5;
  int qbase = grp*2;

  if (blockIdx.y == 2) {
    // ================= static attention =================
    // [0,34816): kc f32[128][68] swizzled (A) | vTh bf16[64][264] (B)
    // [34816,51456): qtl f32[16][68] (A) | P bf16[16][520] (B)
    float* kc  = (float*)smem;
    bf16*  vTh = (bf16*)smem;
    float* qtl = (float*)(smem + 34816);
    bf16*  P   = (bf16*)(smem + 34816);

    float4* q4 = (float4*)qtl;    // stride 17 float4
    float4* k4 = (float4*)kc;     // stride 17 float4

    {
      int m = tid >> 4, jc = tid & 15;
      q4[m*17 + jc] = *(const float4*)(qkc + ((long)(lt*NN + qt*16 + m))*128 + jc*4);
    }

    float S[2][16];
    for (int p = 0; p < 4; ++p) {
      __syncthreads();
      for (int i = tid; i < 2048; i += 256) {
        int m = i >> 4, jc = i & 15;
        k4[m*17 + (jc ^ ((m >> 2) & 3))] =
          *(const float4*)(qkc + ((long)(lt*NN + p*128 + m))*128 + 64 + jc*4);
      }
      __syncthreads();
      float acc00 = 0.f, acc01 = 0.f, acc02 = 0.f, acc03 = 0.f;
      float acc10 = 0.f, acc11 = 0.f, acc12 = 0.f, acc13 = 0.f;
      #pragma unroll 4
      for (int jc = 0; jc < 16; ++jc) {
        float4 q0 = q4[(qbase+0)*17 + jc];
        float4 q1 = q4[(qbase+1)*17 + jc];
        float4 kv;
        int m0 = tx;
        kv = k4[m0*17 + (jc ^ ((m0 >> 2) & 3))];
        acc00 += q0.x*kv.x + q0.y*kv.y + q0.z*kv.z + q0.w*kv.w;
        acc10 += q1.x*kv.x + q1.y*kv.y + q1.z*kv.z + q1.w*kv.w;
        int m1 = tx + 32;
        kv = k4[m1*17 + (jc ^ ((m1 >> 2) & 3))];
        acc01 += q0.x*kv.x + q0.y*kv.y + q0.z*kv.z + q0.w*kv.w;
        acc11 += q1.x*kv.x + q1.y*kv.y + q1.z*kv.z + q1.w*kv.w;
        int m2 = tx + 64;
        kv = k4[m2*17 + (jc ^ ((m2 >> 2) & 3))];
        acc02 += q0.x*kv.x + q0.y*kv.y + q0.z*kv.z + q0.w*kv.w;
        acc12 += q1.x*kv.x + q1.y*kv.y + q1.z*kv.z + q1.w*kv.w;
        int m3 = tx + 96;
        kv = k4[m3*17 + (jc ^ ((m3 >> 2) & 3))];
        acc03 += q0.x*kv.x + q0.y*kv.y + q0.z*kv.z + q0.w*kv.w;
        acc13 += q1.x*kv.x + q1.y*kv.y + q1.z*kv.z + q1.w*kv.w;
      }
      S[0][p*4+0] = acc00; S[0][p*4+1] = acc01; S[0][p*4+2] = acc02; S[0][p*4+3] = acc03;
      S[1][p*4+0] = acc10; S[1][p*4+1] = acc11; S[1][p*4+2] = acc12; S[1][p*4+3] = acc13;
    }
    __syncthreads();   // kc + qtl dead

    #pragma unroll
    for (int qi = 0; qi < 2; ++qi) {
      #pragma unroll
      for (int ig = 0; ig < 16; ++ig) S[qi][ig] *= SCALEV;
      float lm = -INFINITY;
      #pragma unroll
      for (int ig = 0; ig < 16; ++ig) {
        bool keep = ((msk[(qt*16 + qbase + qi)*16 + ig] >> tx) & 1u) != 0u;
        float v = keep ? S[qi][ig] : NEGV;
        S[qi][ig] = v;
        lm = fmaxf(lm, v);
      }
      #pragma unroll
      for (int mk = 1; mk < 32; mk <<= 1) lm = fmaxf(lm, __shfl_xor(lm, mk, 64));
      float se = 0.f;
      #pragma unroll
      for (int ig = 0; ig < 16; ++ig) {
        float ev = __expf(S[qi][ig] - lm);
        S[qi][ig] = ev;
        se += ev;
      }
      #pragma unroll
      for (int mk = 1; mk < 32; mk <<= 1) se += __shfl_xor(se, mk, 64);
      float inv = 1.f / se;
      bf16* prow = P + (qbase + qi)*520;
      #pragma unroll
      for (int ig = 0; ig < 16; ++ig)
        prow[tx + 32*ig] = f2b(S[qi][ig]*inv);
    }

    int w = tid >> 6, l = tid & 63;
    int arow = l & 15, kgrp = l >> 4;
    facc4 acc = {0.f, 0.f, 0.f, 0.f};
    for (int kh = 0; kh < 2; ++kh) {
      __syncthreads();
      for (int i = tid; i < 2048; i += 256) {
        int m2 = (i & 127) << 1;
        int cc = (i >> 7) << 2;
        const bf16* gp = vvc + ((long)(lt*NN + kh*256 + m2))*128 + 64 + cc;
        ushort4 a = *(const ushort4*)(gp);
        ushort4 b = *(const ushort4*)(gp + 128);
        *(unsigned*)(vTh + (cc+0)*264 + m2) = (unsigned)a.x | ((unsigned)b.x << 16);
        *(unsigned*)(vTh + (cc+1)*264 + m2) = (unsigned)a.y | ((unsigned)b.y << 16);
        *(unsigned*)(vTh + (cc+2)*264 + m2) = (unsigned)a.z | ((unsigned)b.z << 16);
        *(unsigned*)(vTh + (cc+3)*264 + m2) = (unsigned)a.w | ((unsigned)b.w << 16);
      }
      __syncthreads();
      const bf16* pa = P + arow*520 + kh*256 + kgrp*8;
      const bf16* pb = vTh + (w*16 + arow)*264 + kgrp*8;
      #pragma unroll
      for (int ks = 0; ks < 8; ++ks) {
        bfrag8 av = *(const bfrag8*)(pa + ks*32);
        bfrag8 bv = *(const bfrag8*)(pb + ks*32);
        acc = __builtin_amdgcn_mfma_f32_16x16x32_bf16(av, bv, acc, 0, 0, 0);
      }
    }
    long rb = ((long)gt*NN + qt*16)*64 + w*16 + arow;
    #pragma unroll
    for (int r = 0; r < 4; ++r) {
      int row = kgrp*4 + r;
      resid[rb + (long)row*64] += acc[r];
    }
    return;
  }

  // ================= dynamic attention (h = blockIdx.y) =================
  // [0,33280): sc f32[16][520] (A) | vT bf16[32][520] (B)
  // [33280,51712): kt f32[128][36] (A) | p_lds bf16[16][520] (B)
  // [49920,52096): red f32[2][272]; [51712,52224): ulds; [52224,52288): means
  float* sc    = (float*)smem;
  bf16*  vT    = (bf16*)smem;
  float* kt    = (float*)(smem + 33280);
  bf16*  p_lds = (bf16*)(smem + 33280);
  float* red   = (float*)(smem + 49920);
  float* ulds  = (float*)(smem + 51712);
  float* means = (float*)(smem + 52224);

  int h = blockIdx.y;
  int qce = h*32, kce = 64 + h*32;

  float4 q0r[8], q1r[8];
  {
    const float* qp = qkx + ((long)(lt*NN + qt*16 + qbase))*128 + qce;
    #pragma unroll
    for (int j = 0; j < 8; ++j) q0r[j] = *(const float4*)(qp + j*4);
    #pragma unroll
    for (int j = 0; j < 8; ++j) q1r[j] = *(const float4*)(qp + 128 + j*4);
  }

  float S[2][16];
  for (int p = 0; p < 4; ++p) {
    __syncthreads();
    for (int i = tid; i < 1024; i += 256) {
      int row = i >> 3, jj = (i & 7) << 2;
      *(float4*)(kt + row*36 + jj) =
        *(const float4*)(qkx + ((long)(lt*NN + p*128 + row))*128 + kce + jj);
    }
    __syncthreads();
    #pragma unroll
    for (int ii = 0; ii < 4; ++ii) {
      int m = tx + 32*ii;
      const float4* kr4 = (const float4*)(kt + m*36);
      float4 k0 = kr4[0], k1 = kr4[1], k2 = kr4[2], k3 = kr4[3];
      float4 k4 = kr4[4], k5 = kr4[5], k6 = kr4[6], k7 = kr4[7];
      // numpy einsum baseline-SIMD emulation: 4 lanes, sequential unfused
      // mul+add per lane over d = l, l+4, ..., l+28; SSE3 hadd tree at end.
      {
        float v0 = 0.f, v1 = 0.f, v2 = 0.f, v3 = 0.f;
        MULADD4(q0r[0], k0); MULADD4(q0r[1], k1); MULADD4(q0r[2], k2); MULADD4(q0r[3], k3);
        MULADD4(q0r[4], k4); MULADD4(q0r[5], k5); MULADD4(q0r[6], k6); MULADD4(q0r[7], k7);
        float s = __fadd_rn(__fadd_rn(v0, v1), __fadd_rn(v2, v3));
        s = s * 0.125f;
        S[0][p*4+ii] = s;
        sc[(qbase+0)*520 + p*128 + m] = s;
      }
      {
        float v0 = 0.f, v1 = 0.f, v2 = 0.f, v3 = 0.f;
        MULADD4(q1r[0], k0); MULADD4(q1r[1], k1); MULADD4(q1r[2], k2); MULADD4(q1r[3], k3);
        MULADD4(q1r[4], k4); MULADD4(q1r[5], k5); MULADD4(q1r[6], k6); MULADD4(q1r[7], k7);
        float s = __fadd_rn(__fadd_rn(v0, v1), __fadd_rn(v2, v3));
        s = s * 0.125f;
        S[1][p*4+ii] = s;
        sc[(qbase+1)*520 + p*128 + m] = s;
      }
    }
  }
  __syncthreads();
  // numpy pairwise mean: 4 base-blocks of 128, 8 strided accumulators each
  if (tid < 128) {
    int row = tid >> 3, b = (tid >> 1) & 3, hh = tid & 1;
    const float* a = sc + row*520 + b*128 + hh*4;
    float4 r4 = *(const float4*)a;
    #pragma unroll
    for (int i = 8; i < 128; i += 8) {
      float4 v = *(const float4*)(a + i);
      r4.x = __fadd_rn(r4.x, v.x); r4.y = __fadd_rn(r4.y, v.y);
      r4.z = __fadd_rn(r4.z, v.z); r4.w = __fadd_rn(r4.w, v.w);
    }
    ulds[row*8 + b*2 + hh] = __fadd_rn(__fadd_rn(r4.x, r4.y), __fadd_rn(r4.z, r4.w));
  }
  __syncthreads();
  if (tid < 16) {
    const float* ur = ulds + tid*8;
    float p0 = __fadd_rn(ur[0], ur[1]);
    float p1 = __fadd_rn(ur[2], ur[3]);
    float p2 = __fadd_rn(ur[4], ur[5]);
    float p3 = __fadd_rn(ur[6], ur[7]);
    means[tid] = __fadd_rn(__fadd_rn(p0, p1), __fadd_rn(p2, p3)) * (1.f/512.f);
  }
  __syncthreads();

  long obase = ((long)(gt*2 + h))*NN*NN;
  #pragma unroll
  for (int qi = 0; qi < 2; ++qi) {
    float mn = means[qbase + qi];
    unsigned kmask = 0; float lm = -INFINITY;
    #pragma unroll
    for (int ig = 0; ig < 16; ++ig) {
      if (S[qi][ig] >= mn) { kmask |= (1u << ig); lm = fmaxf(lm, S[qi][ig]); }
    }
    #pragma unroll
    for (int mk = 1; mk < 32; mk <<= 1) lm = fmaxf(lm, __shfl_xor(lm, mk, 64));
    float e[16]; float se = 0.f;
    #pragma unroll
    for (int ig = 0; ig < 16; ++ig) {
      e[ig] = ((kmask >> ig) & 1u) ? __expf(S[qi][ig] - lm) : 0.f;
      se += e[ig];
    }
    #pragma unroll
    for (int mk = 1; mk < 32; mk <<= 1) se += __shfl_xor(se, mk, 64);
    float inv = 1.f/se;
    float* rowp = attn_out + obase + (long)(qt*16 + qbase + qi)*NN;
    bf16* prow = p_lds + (qbase + qi)*520;
    #pragma unroll
    for (int ig = 0; ig < 16; ++ig) {
      float pr = e[ig]*inv;
      rowp[tx + 32*ig] = pr;
      prow[tx + 32*ig] = f2b(pr);
    }
  }

  for (int i = tid; i < 2048; i += 256) {
    int m2 = (i & 255) << 1;
    int cc = (i >> 8) << 2;
    const bf16* gp = vvc + ((long)(lt*NN + m2))*128 + qce + cc;
    ushort4 a = *(const ushort4*)(gp);
    ushort4 b = *(const ushort4*)(gp + 128);
    *(unsigned*)(vT + (cc+0)*520 + m2) = (unsigned)a.x | ((unsigned)b.x << 16);
    *(unsigned*)(vT + (cc+1)*520 + m2) = (unsigned)a.y | ((unsigned)b.y << 16);
    *(unsigned*)(vT + (cc+2)*520 + m2) = (unsigned)a.z | ((unsigned)b.z << 16);
    *(unsigned*)(vT + (cc+3)*520 + m2) = (unsigned)a.w | ((unsigned)b.w << 16);
  }
  __syncthreads();

  {
    int w = tid >> 6, l = tid & 63;
    int nh = w & 1, kh = w >> 1;
    int arow = l & 15, kgrp = l >> 4;
    facc4 acc = {0.f, 0.f, 0.f, 0.f};
    const bf16* pa = p_lds + arow*520 + kh*256 + kgrp*8;
    const bf16* pb = vT + (nh*16 + arow)*520 + kh*256 + kgrp*8;
    #pragma unroll
    for (int ks = 0; ks < 8; ++ks) {
      bfrag8 av = *(const bfrag8*)(pa + ks*32);
      bfrag8 bv = *(const bfrag8*)(pb + ks*32);
      acc = __builtin_amdgcn_mfma_f32_16x16x32_bf16(av, bv, acc, 0, 0, 0);
    }
    if (w >= 2) {
      #pragma unroll
      for (int r = 0; r < 4; ++r)
        red[nh*272 + (kgrp*4 + r)*17 + arow] = acc[r];
    }
    __syncthreads();
    if (w < 2) {
      long rb = ((long)gt*NN + qt*16)*64 + h*32 + nh*16 + arow;
      #pragma unroll
      for (int r = 0; r < 4; ++r) {
        int row = kgrp*4 + r;
        resid[rb + (long)row*64] += acc[r] + red[nh*272 + row*17 + arow];
      }
    }
  }
}

// ---------------- LN1 fused into MLP gemm1 (K=64, NC=128) ----------------
__global__ __launch_bounds__(256) void k_mlp1(
  const float* __restrict__ resid, const float* __restrict__ g1, const float* __restrict__ b1,
  const float* __restrict__ B, const float* __restrict__ bias, float* __restrict__ C)
{
  __shared__ float As[64][68];
  __shared__ float Bs[64][68];
  int rt = blockIdx.x, bcn = blockIdx.y;
  int tid = threadIdx.x;
  int tx = tid & 15, ty = tid >> 4;
  int wave = tid >> 6, lane = tid & 63;
  // LN stage: wave w handles rows w, w+4, ... (lane = column) — same wsum64 as k_ln1
  for (int rr = wave; rr < 64; rr += 4) {
    float v = resid[((long)rt*64 + rr)*64 + lane];
    float m = wsum64(v)*(1.f/64.f);
    float d = v - m;
    float var = wsum64(d*d)*(1.f/64.f);
    As[lane][rr] = d*rsqrtf(var + 1e-5f)*g1[lane] + b1[lane];
  }
  #pragma unroll
  for (int i = 0; i < 4; ++i) {
    int t = i*256 + tid;
    int m = t >> 4, kq = (t & 15)*4;
    float4 bv = *(const float4*)&B[(long)(bcn*64 + m)*64 + kq];
    Bs[kq+0][m] = bv.x; Bs[kq+1][m] = bv.y; Bs[kq+2][m] = bv.z; Bs[kq+3][m] = bv.w;
  }
  __syncthreads();
  float acc[4][4] = {{0.f}};
  #pragma unroll 8
  for (int kk = 0; kk < 64; ++kk) {
    float4 a4 = *(const float4*)&As[kk][ty*4];
    float4 b4 = *(const float4*)&Bs[kk][tx*4];
    acc[0][0] += a4.x*b4.x; acc[0][1] += a4.x*b4.y; acc[0][2] += a4.x*b4.z; acc[0][3] += a4.x*b4.w;
    acc[1][0] += a4.y*b4.x; acc[1][1] += a4.y*b4.y; acc[1][2] += a4.y*b4.z; acc[1][3] += a4.y*b4.w;
    acc[2][0] += a4.z*b4.x; acc[2][1] += a4.z*b4.y; acc[2][2] += a4.z*b4.z; acc[2][3] += a4.z*b4.w;
    acc[3][0] += a4.w*b4.x; acc[3][1] += a4.w*b4.y; acc[3][2] += a4.w*b4.z; acc[3][3] += a4.w*b4.w;
  }
  #pragma unroll
  for (int i = 0; i < 4; ++i) {
    long ro = (long)(rt*64 + ty*4 + i)*128 + bcn*64 + tx*4;
    #pragma unroll
    for (int j = 0; j < 4; ++j) C[ro + j] = acc[i][j] + bias[bcn*64 + tx*4 + j];
  }
}

// ---------------- LN2 + leaky + PE fused into mha in-projection (K=64, NC=192, bf16 out) ----
__global__ __launch_bounds__(256) void k_mha_in(
  const float* __restrict__ mlpo, const float* __restrict__ resid,
  const float* __restrict__ g2, const float* __restrict__ b2,
  const float* __restrict__ B, const float* __restrict__ bias, bf16* __restrict__ C)
{
  __shared__ float As[64][68];
  __shared__ float Bs[64][68];
  int rt = blockIdx.x, bcn = blockIdx.y;
  int tid = threadIdx.x;
  int tx = tid & 15, ty = tid >> 4;
  int wave = tid >> 6, lane = tid & 63;
  for (int rr = wave; rr < 64; rr += 4) {
    long r = (long)rt*64 + rr;
    float v = mlpo[r*64 + lane] + resid[r*64 + lane];
    float m = wsum64(v)*(1.f/64.f);
    float d = v - m;
    float var = wsum64(d*d)*(1.f/64.f);
    float y = d*rsqrtf(var + 1e-5f)*g2[lane] + b2[lane];
    y = lk(y);
    float tf = (float)(r / NN);
    float dv = __expf(-(float)(lane & ~1) * 0.14391156831212787f);
    float pe = (lane & 1) ? cosf(tf*dv) : sinf(tf*dv);
    As[lane][rr] = y + pe;
  }
  #pragma unroll
  for (int i = 0; i < 4; ++i) {
    int t = i*256 + tid;
    int m = t >> 4, kq = (t & 15)*4;
    float4 bv = *(const float4*)&B[(long)(bcn*64 + m)*64 + kq];
    Bs[kq+0][m] = bv.x; Bs[kq+1][m] = bv.y; Bs[kq+2][m] = bv.z; Bs[kq+3][m] = bv.w;
  }
  __syncthreads();
  float acc[4][4] = {{0.f}};
  #pragma unroll 8
  for (int kk = 0; kk < 64; ++kk) {
    float4 a4 = *(const float4*)&As[kk][ty*4];
    float4 b4 = *(const float4*)&Bs[kk][tx*4];
    acc[0][0] += a4.x*b4.x; acc[0][1] += a4.x*b4.y; acc[0][2] += a4.x*b4.z; acc[0][3] += a4.x*b4.w;
    acc[1][0] += a4.y*b4.x; acc[1][1] += a4.y*b4.y; acc[1][2] += a4.y*b4.z; acc[1][3] += a4.y*b4.w;
    acc[2][0] += a4.z*b4.x; acc[2][1] += a4.z*b4.y; acc[2][2] += a4.z*b4.z; acc[2][3] += a4.z*b4.w;
    acc[3][0] += a4.w*b4.x; acc[3][1] += a4.w*b4.y; acc[3][2] += a4.w*b4.z; acc[3][3] += a4.w*b4.w;
  }
  #pragma unroll
  for (int i = 0; i < 4; ++i) {
    long ro = (long)(rt*64 + ty*4 + i)*192 + bcn*64 + tx*4;
    #pragma unroll
    for (int j = 0; j < 4; ++j) C[ro + j] = f2b(acc[i][j] + bias[bcn*64 + tx*4 + j]);
  }
}

// ---------------- head ----------------
__global__ __launch_bounds__(64) void k_head(
  const bf16* __restrict__ mqkv, const float* __restrict__ rts,
  const float* __restrict__ mow, const float* __restrict__ mob,
  const float* __restrict__ xsw, const float* __restrict__ xtw, const float* __restrict__ xtb,
  const float* __restrict__ hw, const float* __restrict__ hb,
  const float* __restrict__ linw, const float* __restrict__ linb,
  float* __restrict__ out)
{
  int n = blockIdx.x, o = threadIdx.x;
  __shared__ float ps[TT];
  __shared__ float buf[64], buf2[64];
  float mq = b2f(mqkv[((long)(TT-1)*NN + n)*192 + o]);
  for (int s = 0; s < TT; ++s) {
    float v = mq * b2f(mqkv[((long)s*NN + n)*192 + 64 + o]);
    v = wsum64(v);
    if (o == 0) ps[s] = v * SCALEV;
  }
  __syncthreads();
  float x = (o < TT) ? ps[o] : -INFINITY;
  float mx = wmax64(x);
  float e = (o < TT) ? __expf(x - mx) : 0.f;
  float se = wsum64(e);
  if (o < TT) ps[o] = e / se;
  __syncthreads();
  float acc = 0.f;
  for (int s = 0; s < TT; ++s) acc += ps[s]*b2f(mqkv[((long)s*NN + n)*192 + 128 + o]);
  buf[o] = acc;
  __syncthreads();
  float acc2 = mob[o];
  for (int k = 0; k < 64; ++k) acc2 += buf[k]*mow[o*64 + k];
  float m2 = wsum64(acc2)*(1.f/64.f);
  float d2 = acc2 - m2;
  float var2 = wsum64(d2*d2)*(1.f/64.f);
  float a = d2*rsqrtf(var2 + 1e-5f);
  float rt = rts[(long)n*64 + o];
  __syncthreads();
  buf[o] = a; buf2[o] = rt;
  __syncthreads();
  float pre = xtb[o];
  for (int k = 0; k < 64; ++k) pre += buf[k]*xsw[o*64 + k] + buf2[k]*xtw[o*64 + k];
  float zg = sgm(pre);
  float u = zg*a + (1.f - zg)*rt;
  __syncthreads();
  buf[o] = u;
  __syncthreads();
  float f = hb[o];
  for (int k = 0; k < 64; ++k) f += buf[k]*hw[o*64 + k];
  f = lk(f);
  float tot = wsum64(f * linw[o]);
  if (o == 0) out[n] = tot + linb[0];
}

// =======================================================================
extern "C" void kernel_launch(void* const* d_in, const int* in_sizes, int n_in,
                              void* d_out, int out_size, void* d_ws, size_t ws_size,
                              hipStream_t stream)
{
  const float* x    = (const float*)d_in[0];
  const int*   ei   = (const int*)  d_in[1];
  const float* fcw  = (const float*)d_in[2];
  const float* fcb  = (const float*)d_in[3];
  const float* wih0 = (const float*)d_in[4];
  const float* whh0 = (const float*)d_in[5];
  const float* bih0 = (const float*)d_in[6];
  const float* bhh0 = (const float*)d_in[7];
  const float* wih1 = (const float*)d_in[8];
  const float* whh1 = (const float*)d_in[9];
  const float* bih1 = (const float*)d_in[10];
  const float* bhh1 = (const float*)d_in[11];
  const float* dmqw = (const float*)d_in[12];
  const float* dmkw = (const float*)d_in[13];
  const float* dmvw = (const float*)d_in[14];
  const float* dmvb = (const float*)d_in[15];
  const float* ssqw = (const float*)d_in[16];
  const float* sskw = (const float*)d_in[17];
  const float* ssvw = (const float*)d_in[18];
  const float* ssvb = (const float*)d_in[19];
  const float* ln1g = (const float*)d_in[20];
  const float* ln1b = (const float*)d_in[21];
  const float* ln2g = (const float*)d_in[22];
  const float* ln2b = (const float*)d_in[23];
  const float* mw1  = (const float*)d_in[24];
  const float* mb1  = (const float*)d_in[25];
  const float* mw2  = (const float*)d_in[26];
  const float* mb2  = (const float*)d_in[27];
  const float* mhw  = (const float*)d_in[28];
  const float* mhb  = (const float*)d_in[29];
  const float* mow  = (const float*)d_in[30];
  const float* mob  = (const float*)d_in[31];
  const float* gxsw = (const float*)d_in[32];
  const float* gxtw = (const float*)d_in[33];
  const float* gxtb = (const float*)d_in[34];
  const float* ghw  = (const float*)d_in[35];
  const float* ghb  = (const float*)d_in[36];
  const float* linw = (const float*)d_in[37];
  const float* linb = (const float*)d_in[38];

  // ---- workspace layout (~43.6 MB envelope, unchanged) ----
  char* base = (char*)d_ws;
  float*  xs    = (float*)(base);                 // xs f32; later mlpo f32
  char*   Rb    = base + 7864320;                 // shared region (15.73 MB):
  float*  qkc   = (float*)Rb;                     //   per-chunk qs|ks f32 (5.24MB, TCH=20)
  bf16*   vvc   = (bf16*)(Rb + 5242880);          //   per-chunk v|vs bf16 (2.62MB)
  float*  qkx   = (float*)(Rb + 7864320);         //   per-chunk exact q|k f32 (5.24MB)
  float*  mlph  = (float*)Rb;                     //   later: mlp hidden f32 (15.73MB)
  bf16*   mqkv  = (bf16*)Rb;                      //   later: mha qkv bf16 (11.8MB)
  bf16*   g0    = (bf16*)(base + 23592960);
  float*  resid = (float*)(base + 27525120);
  float*  rts   = (float*)(base + 43253760);
  unsigned int* msk = (unsigned int*)(base + 43384832);
  float*  Wall  = (float*)(base + 43417600);      // 6*4096 f32 (q|k|qs|ks|v|vs)
  float*  bcV   = (float*)(base + 43515904);      // 128 f32
  float*  mlpo  = xs;
  float*  outb  = (float*)d_out;
  float*  attn  = outb + 512;
  // gi staged in d_out's attn region — dead before k_attn writes probs
  float*  gi    = (float*)((char*)d_out + 2048);

  k_pack<<<dim3(98), 256, 0, stream>>>(dmqw, dmkw, ssqw, sskw, dmvw, ssvw, dmvb, ssvb, ei, msk, Wall, bcV);
  k_fcin<<<dim3(TN*64/256), 256, 0, stream>>>(x, fcw, fcb, xs, resid);
  // GRU layer 0
  k_gemm<float,float><<<dim3(480, 3), 256, 0, stream>>>(xs, wih0, bih0, gi, 64, 192, 1);
  k_gru<<<dim3(NN), 192, 0, stream>>>(gi, whh0, bhh0, g0, nullptr, 0);
  // GRU layer 1
  k_gemm<bf16,float><<<dim3(480, 3), 256, 0, stream>>>(g0, wih1, bih1, gi, 64, 192, 1);
  k_gru<<<dim3(NN), 192, 0, stream>>>(gi, whh1, bhh1, nullptr, rts, 1);
  // attention in 3 t-chunks of 20 (dyn h=0,1 and static merged in one launch)
  for (int tc = 0; tc < NCHK; ++tc) {
    const float* xsc = xs + (size_t)tc*TCH*NN*64;
    k_proj<<<dim3(TCH*NN/64, 6), 256, 0, stream>>>(xsc, Wall, bcV, qkx, qkc, vvc);
    k_attn<<<dim3(32, 3, TCH), 256, 0, stream>>>(qkx, qkc, vvc, msk, attn, resid, tc);
  }
  // LN1+MLP1 -> MLP2 -> LN2+PE+mha-in -> head
  k_mlp1<<<dim3(480, 2), 256, 0, stream>>>(resid, ln1g, ln1b, mw1, mb1, mlph);
  k_gemm<float,float><<<dim3(480, 1), 256, 0, stream>>>(mlph, mw2, mb2, mlpo, 128, 64, 0);
  k_mha_in<<<dim3(480, 3), 256, 0, stream>>>(mlpo, resid, ln2g, ln2b, mhw, mhb, mqkv);
  k_head<<<dim3(NN), 64, 0, stream>>>(mqkv, rts, mow, mob, gxsw, gxtw, gxtb, ghw, ghb, linw, linb, outb);
}